// Round 2
// baseline (4179.985 us; speedup 1.0000x reference)
//
#include <hip/hip_runtime.h>
#include <math.h>

// VQ-VAE forward, fp32. MI355X / gfx950.
// Stages: prep -> conv1 -> conv2 -> conv3 -> vq (fused dist/argmin/scatter/loss) -> 4x(deconv1, deconv2)
// Workspace layout (floats):
//   [0)            h1  33,554,432  (reused per-chunk as g: 16,777,216)
//   [33554432)     h2  16,777,216
//   [50331648)     enc  4,194,304
//   [54525952)     qdec 4,194,304
//   [58720256)     w3T     16,384
//   [58736640)     dw2T    12,288
//   [58748928)     enorm    2,048
//   [58750976)     loss        16 (padded)

#define LD4(p) (*(const float4*)(p))
#define FMA4(A, s, W) { A.x += (s)*(W).x; A.y += (s)*(W).y; A.z += (s)*(W).z; A.w += (s)*(W).w; }
#define STOREL(dst, A, BB) { float4 t_; t_.x = leaky((A).x + (BB).x); t_.y = leaky((A).y + (BB).y); \
                             t_.z = leaky((A).z + (BB).z); t_.w = leaky((A).w + (BB).w); *(float4*)(dst) = t_; }

__device__ __forceinline__ float leaky(float v) { return v >= 0.f ? v : 0.01f * v; }

// swizzled h-offset within a 64-float row: XOR the h-quad index with a row-derived nibble
#define FSWZ(h, c) ((((((h) >> 2) ^ (((c) >> 2) & 15)) << 2)) | ((h) & 3))
#define ESWZ(h, k) ((((((h) >> 2) ^ (((k) >> 1) & 15)) << 2)) | ((h) & 3))

// ---------------------------------------------------------------- prep
__global__ __launch_bounds__(256) void k_prep(const float* __restrict__ w3, const float* __restrict__ dw2,
                                              const float* __restrict__ emb,
                                              float* __restrict__ w3T, float* __restrict__ dw2T,
                                              float* __restrict__ enorm, float* __restrict__ loss) {
    int t = blockIdx.x * 256 + threadIdx.x;
    if (t == 0) loss[0] = 0.f;
    if (t < 16384) {                       // w3T[d][c] = w3[c][d]  (w3 is [1,1,256,64])
        int d = t >> 8, c = t & 255;
        w3T[d * 256 + c] = w3[c * 64 + d];
    }
    int u = t - 16384;                     // dw2T[kk][o][i] = dw2[kk][i][o]  (dw2 [4,4,256,3])
    if (u >= 0 && u < 12288) {
        int i = u & 255; int rest = u >> 8; int o = rest % 3; int kk = rest / 3;
        dw2T[(kk * 3 + o) * 256 + i] = dw2[(kk * 256 + i) * 3 + o];
    }
    int v = t - (16384 + 12288);           // enorm[k] = ||emb[k]||^2
    if (v >= 0 && v < 2048) {
        const float* e = emb + v * 64;
        float s = 0.f;
        #pragma unroll
        for (int h = 0; h < 64; ++h) s += e[h] * e[h];
        enorm[v] = s;
    }
}

// ---------------------------------------------------------------- conv1: x[16,256,256,3] -> h1[16,128,128,128]
__global__ __launch_bounds__(128) void k_conv1(const float* __restrict__ x, const float* __restrict__ w1,
                                               const float* __restrict__ b1, float* __restrict__ h1) {
    __shared__ float smem[120]; // [iy 4][ix 10][c 3]
    int bx = blockIdx.x;
    int xg = bx & 31, y = (bx >> 5) & 127, b = bx >> 12;
    int x0 = xg << 2;
    int tid = threadIdx.x;
    if (tid < 120) {
        int c = tid % 3, sp = tid / 3;
        int iy = sp / 10, ix = sp - iy * 10;
        int gy = 2 * y - 1 + iy, gx = 2 * x0 - 1 + ix;
        float v = 0.f;
        if ((unsigned)gy < 256u && (unsigned)gx < 256u)
            v = x[((b * 256 + gy) * 256 + gx) * 3 + c];
        smem[tid] = v;
    }
    __syncthreads();
    int o = tid;
    float a0 = 0.f, a1 = 0.f, a2 = 0.f, a3 = 0.f;
    #pragma unroll
    for (int ky = 0; ky < 4; ++ky)
        #pragma unroll
        for (int kx = 0; kx < 4; ++kx)
            #pragma unroll
            for (int c = 0; c < 3; ++c) {
                float wv = w1[((ky * 4 + kx) * 3 + c) * 128 + o];
                a0 += smem[(ky * 10 + kx + 0) * 3 + c] * wv;
                a1 += smem[(ky * 10 + kx + 2) * 3 + c] * wv;
                a2 += smem[(ky * 10 + kx + 4) * 3 + c] * wv;
                a3 += smem[(ky * 10 + kx + 6) * 3 + c] * wv;
            }
    float bb = b1[o];
    int ob = ((b * 128 + y) * 128 + x0) * 128 + o;
    h1[ob]       = leaky(a0 + bb);
    h1[ob + 128] = leaky(a1 + bb);
    h1[ob + 256] = leaky(a2 + bb);
    h1[ob + 384] = leaky(a3 + bb);
}

// ---------------------------------------------------------------- conv2: h1 -> h2[16,64,64,256]
__global__ __launch_bounds__(256) void k_conv2(const float* __restrict__ h1, const float* __restrict__ w2,
                                               const float* __restrict__ b2, float* __restrict__ h2) {
    __shared__ float smem[12800]; // [iy 10][ix 10][c 128]
    int bx = blockIdx.x;
    int tx = bx & 15, ty = (bx >> 4) & 15, b = bx >> 8;
    int x0 = tx << 2, y0 = ty << 2;
    int tid = threadIdx.x;
    #pragma unroll
    for (int j = 0; j < 50; ++j) {
        int e = j * 256 + tid;
        int c = e & 127, sp = e >> 7;
        int iy = sp / 10, ix = sp - iy * 10;
        int gy = 2 * y0 - 1 + iy, gx = 2 * x0 - 1 + ix;
        float v = 0.f;
        if ((unsigned)gy < 128u && (unsigned)gx < 128u)
            v = h1[((b * 128 + gy) * 128 + gx) * 128 + c];
        smem[e] = v;
    }
    __syncthreads();
    int og = (tid & 63) << 2;   // 4 consecutive out channels
    int pg = tid >> 6;          // out row within tile (wave-uniform)
    float4 a0 = {0,0,0,0}, a1 = a0, a2 = a0, a3 = a0;
    for (int kk = 0; kk < 16; ++kk) {
        int ky = kk >> 2, kx = kk & 3;
        const float* wb = w2 + (kk * 128) * 256 + og;
        int r = (2 * pg + ky) * 10 + kx;
        const float* p0 = smem + (r + 0) * 128;
        const float* p1 = smem + (r + 2) * 128;
        const float* p2 = smem + (r + 4) * 128;
        const float* p3 = smem + (r + 6) * 128;
        #pragma unroll 2
        for (int c = 0; c < 128; c += 4) {
            float4 w0 = LD4(wb + (c + 0) * 256);
            float4 w1v = LD4(wb + (c + 1) * 256);
            float4 w2v = LD4(wb + (c + 2) * 256);
            float4 w3v = LD4(wb + (c + 3) * 256);
            float4 i0 = LD4(p0 + c), i1 = LD4(p1 + c), i2 = LD4(p2 + c), i3 = LD4(p3 + c);
            FMA4(a0, i0.x, w0) FMA4(a0, i0.y, w1v) FMA4(a0, i0.z, w2v) FMA4(a0, i0.w, w3v)
            FMA4(a1, i1.x, w0) FMA4(a1, i1.y, w1v) FMA4(a1, i1.z, w2v) FMA4(a1, i1.w, w3v)
            FMA4(a2, i2.x, w0) FMA4(a2, i2.y, w1v) FMA4(a2, i2.z, w2v) FMA4(a2, i2.w, w3v)
            FMA4(a3, i3.x, w0) FMA4(a3, i3.y, w1v) FMA4(a3, i3.z, w2v) FMA4(a3, i3.w, w3v)
        }
    }
    float4 bb = LD4(b2 + og);
    int ob = ((b * 64 + (y0 + pg)) * 64 + x0) * 256 + og;
    STOREL(h2 + ob,       a0, bb)
    STOREL(h2 + ob + 256, a1, bb)
    STOREL(h2 + ob + 512, a2, bb)
    STOREL(h2 + ob + 768, a3, bb)
}

// ---------------------------------------------------------------- conv3: 1x1, h2 -> enc[16,64,64,64]
__global__ __launch_bounds__(256) void k_conv3(const float* __restrict__ h2, const float* __restrict__ w3T,
                                               const float* __restrict__ b3, float* __restrict__ enc) {
    __shared__ float smem[1024]; // 4 pixels x 256 ch
    int bx = blockIdx.x;
    int tid = threadIdx.x;
    *(float4*)(smem + tid * 4) = LD4(h2 + bx * 1024 + tid * 4);
    __syncthreads();
    int p = tid >> 6, d = tid & 63;
    const float* wrow = w3T + d * 256;
    const float* in = smem + p * 256;
    float s0 = 0.f, s1 = 0.f, s2 = 0.f, s3 = 0.f;
    #pragma unroll 4
    for (int c = 0; c < 256; c += 4) {
        float4 iv = LD4(in + c);
        float4 wv = LD4(wrow + c);
        s0 += iv.x * wv.x; s1 += iv.y * wv.y; s2 += iv.z * wv.z; s3 += iv.w * wv.w;
    }
    enc[bx * 256 + tid] = b3[d] + ((s0 + s1) + (s2 + s3));
}

// ---------------------------------------------------------------- fused VQ: dist + argmin + scatter + loss
// Block rb -> (b = rb>>6, w = rb&63), 64 rows (all c). Threads: tr=tid&15 (4 rows), tc=tid>>4 (8 codes/chunk).
__global__ __launch_bounds__(256, 2) void k_vq(const float* __restrict__ enc, const float* __restrict__ emb,
                                               const float* __restrict__ enorm,
                                               float* __restrict__ qdec, float* __restrict__ loss) {
    __shared__ float f_lds[64 * 64];    // [c][h swizzled]
    __shared__ float e_lds[128 * 64];   // [k][h swizzled]
    __shared__ float en_sh[128];
    __shared__ float red_s[16 * 64];
    __shared__ int   red_k[16 * 64];
    __shared__ int   bk_sh[64];

    int rb = blockIdx.x;
    int b = rb >> 6, w = rb & 63;
    int tid = threadIdx.x;
    int cl = tid & 63, hg = tid >> 6;

    // stage f: f[c][h] = enc[b, h, w, c]
    const float* encb = enc + b * 262144 + w * 64;
    #pragma unroll
    for (int hp = 0; hp < 16; ++hp) {
        int h = hp * 4 + hg;
        f_lds[cl * 64 + FSWZ(h, cl)] = encb[h * 4096 + cl];
    }

    int tr = tid & 15, tc = tid >> 4;
    float bestl[4]; int bkl[4];
    #pragma unroll
    for (int i = 0; i < 4; ++i) { bestl[i] = 3.4e38f; bkl[i] = 0; }

    for (int ch = 0; ch < 16; ++ch) {
        __syncthreads();               // f ready (first iter) / previous compute done
        const float* eb = emb + ch * 8192;
        #pragma unroll
        for (int j = 0; j < 32; ++j) {
            int l = j * 256 + tid;     // 0..8191
            int k = l >> 6, h = l & 63;
            e_lds[k * 64 + ESWZ(h, k)] = eb[l];
        }
        if (tid < 128) en_sh[tid] = enorm[ch * 128 + tid];
        __syncthreads();

        float acc[4][8];
        #pragma unroll
        for (int i = 0; i < 4; ++i)
            #pragma unroll
            for (int j = 0; j < 8; ++j) acc[i][j] = 0.f;

        #pragma unroll
        for (int h4 = 0; h4 < 16; ++h4) {
            float4 fv[4];
            #pragma unroll
            for (int i = 0; i < 4; ++i)
                fv[i] = LD4(f_lds + (tr * 4 + i) * 64 + ((h4 ^ tr) << 2));
            #pragma unroll
            for (int j = 0; j < 8; ++j) {
                int k = tc * 8 + j;
                float4 ev = LD4(e_lds + k * 64 + ((h4 ^ ((k >> 1) & 15)) << 2));
                #pragma unroll
                for (int i = 0; i < 4; ++i) {
                    acc[i][j] += fv[i].x * ev.x + fv[i].y * ev.y
                               + fv[i].z * ev.z + fv[i].w * ev.w;
                }
            }
        }
        #pragma unroll
        for (int j = 0; j < 8; ++j) {
            float en = en_sh[tc * 8 + j];
            int kg = ch * 128 + tc * 8 + j;
            #pragma unroll
            for (int i = 0; i < 4; ++i) {
                float s = en - 2.f * acc[i][j];
                if (s < bestl[i]) { bestl[i] = s; bkl[i] = kg; }
            }
        }
    }

    // cross-thread merge: red[tc][row]
    #pragma unroll
    for (int i = 0; i < 4; ++i) {
        red_s[tc * 64 + tr * 4 + i] = bestl[i];
        red_k[tc * 64 + tr * 4 + i] = bkl[i];
    }
    __syncthreads();
    if (tid < 64) {
        float bs = red_s[tid]; int bk = red_k[tid];
        #pragma unroll
        for (int t = 1; t < 16; ++t) {
            float s = red_s[t * 64 + tid]; int k = red_k[t * 64 + tid];
            if (s < bs || (s == bs && k < bk)) { bs = s; bk = k; }
        }
        bk_sh[tid] = bk;
    }
    __syncthreads();

    // epilogue: quant scatter (coalesced over c) + loss
    int bk = bk_sh[cl];
    const float* ev = emb + bk * 64;
    float* qd = qdec + b * 262144 + w * 64 + cl;
    float ls = 0.f;
    #pragma unroll
    for (int hp = 0; hp < 16; ++hp) {
        int h = hp * 4 + hg;
        float e = ev[h];
        float f = f_lds[cl * 64 + FSWZ(h, cl)];
        float d = e - f;
        ls += d * d;
        qd[h * 4096] = e;
    }
    #pragma unroll
    for (int off = 32; off; off >>= 1) ls += __shfl_xor(ls, off, 64);
    if ((tid & 63) == 0) atomicAdd(loss, ls);
}

// ---------------------------------------------------------------- deconv1: qdec[16,64,64,64] -> g[4,128,128,256] (batch chunk)
__global__ __launch_bounds__(256) void k_deconv1(const float* __restrict__ qdec, const float* __restrict__ dw1,
                                                 const float* __restrict__ db1, float* __restrict__ g, int b0) {
    __shared__ float smem[1024]; // [lh 4][lw 4][c 64]
    int bx = blockIdx.x;
    int xg = bx & 31, yg = (bx >> 5) & 31, bl = bx >> 10;
    int b = b0 + bl;
    int x0 = xg << 2, y0 = yg << 2;
    int m0 = yg << 1, n0 = xg << 1;
    int tid = threadIdx.x;
    {
        int e = tid << 2;
        int cc = e & 63, sp = e >> 6;
        int lh = sp >> 2, lw = sp & 3;
        int hh = m0 - 1 + lh, wwc = n0 - 1 + lw;
        float4 v = {0,0,0,0};
        if ((unsigned)hh < 64u && (unsigned)wwc < 64u)
            v = LD4(qdec + ((b * 64 + hh) * 64 + wwc) * 64 + cc);
        *(float4*)(smem + e) = v;
    }
    __syncthreads();
    int og = (tid & 63) << 2;
    int pg = tid >> 6;           // out row within tile (wave-uniform)
    int par = pg & 1;
    int lhb = (pg + 1) >> 1;
    float4 a0 = {0,0,0,0}, a1 = a0, a2 = a0, a3 = a0;
    #pragma unroll
    for (int tky = 0; tky < 2; ++tky) {
        int ky = par + 2 * tky;
        int lh = lhb + tky;
        #pragma unroll
        for (int tkx = 0; tkx < 2; ++tkx) {
            const float* wE = dw1 + ((ky * 4 + 2 * tkx) * 64) * 256 + og;       // even-x taps
            const float* wO = dw1 + ((ky * 4 + 2 * tkx + 1) * 64) * 256 + og;   // odd-x taps
            const float* l0 = smem + (lh * 4 + tkx) * 64;        // px0
            const float* l1 = l0 + 64;                           // px1, px2
            const float* l3 = l0 + 128;                          // px3
            #pragma unroll 2
            for (int i = 0; i < 64; i += 4) {
                float4 we0 = LD4(wE + (i + 0) * 256), we1 = LD4(wE + (i + 1) * 256),
                       we2 = LD4(wE + (i + 2) * 256), we3 = LD4(wE + (i + 3) * 256);
                float4 wo0 = LD4(wO + (i + 0) * 256), wo1 = LD4(wO + (i + 1) * 256),
                       wo2 = LD4(wO + (i + 2) * 256), wo3 = LD4(wO + (i + 3) * 256);
                float4 iA = LD4(l0 + i), iB = LD4(l1 + i), iC = LD4(l3 + i);
                FMA4(a0, iA.x, we0) FMA4(a0, iA.y, we1) FMA4(a0, iA.z, we2) FMA4(a0, iA.w, we3)
                FMA4(a1, iB.x, wo0) FMA4(a1, iB.y, wo1) FMA4(a1, iB.z, wo2) FMA4(a1, iB.w, wo3)
                FMA4(a2, iB.x, we0) FMA4(a2, iB.y, we1) FMA4(a2, iB.z, we2) FMA4(a2, iB.w, we3)
                FMA4(a3, iC.x, wo0) FMA4(a3, iC.y, wo1) FMA4(a3, iC.z, wo2) FMA4(a3, iC.w, wo3)
            }
        }
    }
    float4 bb = LD4(db1 + og);
    int ob = ((bl * 128 + (y0 + pg)) * 128 + x0) * 256 + og;
    STOREL(g + ob,       a0, bb)
    STOREL(g + ob + 256, a1, bb)
    STOREL(g + ob + 512, a2, bb)
    STOREL(g + ob + 768, a3, bb)
}

// ---------------------------------------------------------------- deconv2: g chunk -> recon[4,256,256,3], tanh
__global__ __launch_bounds__(256) void k_deconv2(const float* __restrict__ g, const float* __restrict__ dw2T,
                                                 const float* __restrict__ db2, float* __restrict__ out,
                                                 const float* __restrict__ loss, int b0, int write_loss) {
    int p = blockIdx.x * 256 + threadIdx.x;   // pixel within chunk (4*65536)
    int x = p & 255, y = (p >> 8) & 255, bl = p >> 16;
    int b = b0 + bl;
    float a0 = db2[0], a1 = db2[1], a2 = db2[2];
    #pragma unroll
    for (int tky = 0; tky < 2; ++tky) {
        int ky = (y & 1) + 2 * tky;
        int h = (y - 2 + ky) >> 1;
        if ((unsigned)h >= 128u) continue;
        #pragma unroll
        for (int tkx = 0; tkx < 2; ++tkx) {
            int kx = (x & 1) + 2 * tkx;
            int w = (x - 2 + kx) >> 1;
            if ((unsigned)w >= 128u) continue;
            const float* gb = g + ((bl * 128 + h) * 128 + w) * 256;
            int kk = ky * 4 + kx;
            const float* wr = dw2T + kk * 3 * 256;
            #pragma unroll 4
            for (int i = 0; i < 256; i += 4) {
                float4 gv = LD4(gb + i);
                float4 wa = LD4(wr + i);
                float4 wb = LD4(wr + 256 + i);
                float4 wc = LD4(wr + 512 + i);
                a0 += gv.x * wa.x + gv.y * wa.y + gv.z * wa.z + gv.w * wa.w;
                a1 += gv.x * wb.x + gv.y * wb.y + gv.z * wb.z + gv.w * wb.w;
                a2 += gv.x * wc.x + gv.y * wc.y + gv.z * wc.z + gv.w * wc.w;
            }
        }
    }
    int ob = (b * 65536 + (y << 8) + x) * 3;
    out[ob]     = tanhf(a0);
    out[ob + 1] = tanhf(a1);
    out[ob + 2] = tanhf(a2);
    if (write_loss && blockIdx.x == 0 && threadIdx.x == 0)
        out[3145728] = loss[0] * (1.25f / 4194304.f);
}

// ---------------------------------------------------------------- launch
extern "C" void kernel_launch(void* const* d_in, const int* in_sizes, int n_in,
                              void* d_out, int out_size, void* d_ws, size_t ws_size,
                              hipStream_t stream) {
    const float* x   = (const float*)d_in[0];
    const float* emb = (const float*)d_in[1];
    const float* w1  = (const float*)d_in[2];
    const float* b1  = (const float*)d_in[3];
    const float* w2  = (const float*)d_in[4];
    const float* b2  = (const float*)d_in[5];
    const float* w3  = (const float*)d_in[6];
    const float* b3  = (const float*)d_in[7];
    const float* dw1 = (const float*)d_in[8];
    const float* db1 = (const float*)d_in[9];
    const float* dw2 = (const float*)d_in[10];
    const float* db2 = (const float*)d_in[11];
    float* out = (float*)d_out;
    float* ws  = (float*)d_ws;

    if (ws_size < (size_t)58750992 * 4) return;

    float* h1    = ws;                 // also reused as g (per-4-batch chunk)
    float* g     = ws;
    float* h2    = ws + 33554432;
    float* enc   = ws + 50331648;
    float* qdec  = ws + 54525952;
    float* w3T   = ws + 58720256;
    float* dw2T  = ws + 58736640;
    float* enorm = ws + 58748928;
    float* loss  = ws + 58750976;

    k_prep   <<<120,   256, 0, stream>>>(w3, dw2, emb, w3T, dw2T, enorm, loss);
    k_conv1  <<<65536, 128, 0, stream>>>(x, w1, b1, h1);
    k_conv2  <<<4096,  256, 0, stream>>>(h1, w2, b2, h2);
    k_conv3  <<<16384, 256, 0, stream>>>(h2, w3T, b3, enc);
    k_vq     <<<1024,  256, 0, stream>>>(enc, emb, enorm, qdec, loss);
    for (int b0 = 0; b0 < 16; b0 += 4) {
        k_deconv1<<<4096, 256, 0, stream>>>(qdec, dw1, db1, g, b0);
        k_deconv2<<<1024, 256, 0, stream>>>(g, dw2T, db2, out, loss, b0, (b0 == 12) ? 1 : 0);
    }
}

// Round 3
// 2078.520 us; speedup vs baseline: 2.0110x; 2.0110x over previous
//
#include <hip/hip_runtime.h>
#include <math.h>

// VQ-VAE forward. MI355X / gfx950. bf16-MFMA conv2 + deconv1.
// prep -> pack -> conv1(bf16 out) -> conv2(MFMA) -> conv3 -> vq -> deconv1(MFMA, bf16 g) -> deconv2
// Workspace (float slots):
//   [0)          h1b bf16 (16,777,216 slots) ... later g bf16 (33,554,432 slots)
//   [33554432)   h2 fp32  16,777,216
//   [50331648)   enc fp32  4,194,304
//   [54525952)   qdec bf16 (2,097,152 slots)
//   [56623104)   w3T fp32     16,384
//   [56639488)   dw2T fp32    12,288
//   [56651776)   enorm         2,048
//   [56653824)   loss             16
//   [56653840)   w2p bf16 (262,144 slots)
//   [56915984)   dw1p bf16 (131,072 slots)
//   total 57,047,056 floats = 228.2 MB

typedef short s16x8 __attribute__((ext_vector_type(8)));
typedef float f32x4 __attribute__((ext_vector_type(4)));

#define LD4(p) (*(const float4*)(p))

__device__ __forceinline__ float leaky(float v) { return v >= 0.f ? v : 0.01f * v; }
__device__ __forceinline__ unsigned short f2b(float f) {
    union { float f; unsigned u; } v; v.f = f;
    unsigned r = v.u + 0x7fffu + ((v.u >> 16) & 1u);
    return (unsigned short)(r >> 16);
}
__device__ __forceinline__ float b2f(unsigned short u) {
    union { unsigned u; float f; } v; v.u = ((unsigned)u) << 16; return v.f;
}
__device__ __forceinline__ s16x8 ldz(const unsigned short* p, bool ok) {
    s16x8 z = {0,0,0,0,0,0,0,0};
    return ok ? *(const s16x8*)p : z;
}

// swizzles for VQ LDS
#define FSWZ(h, c) ((((((h) >> 2) ^ (((c) >> 2) & 15)) << 2)) | ((h) & 3))
#define ESWZ(h, k) ((((((h) >> 2) ^ (((k) >> 1) & 15)) << 2)) | ((h) & 3))

// ---------------------------------------------------------------- prep (small fp32 tables)
__global__ __launch_bounds__(256) void k_prep(const float* __restrict__ w3, const float* __restrict__ dw2,
                                              const float* __restrict__ emb,
                                              float* __restrict__ w3T, float* __restrict__ dw2T,
                                              float* __restrict__ enorm, float* __restrict__ loss) {
    int t = blockIdx.x * 256 + threadIdx.x;
    if (t == 0) loss[0] = 0.f;
    if (t < 16384) {                       // w3T[d][c] = w3[c][d]
        int d = t >> 8, c = t & 255;
        w3T[d * 256 + c] = w3[c * 64 + d];
    }
    int u = t - 16384;                     // dw2T[kk][o][i] = dw2[kk][i][o]
    if (u >= 0 && u < 12288) {
        int i = u & 255; int rest = u >> 8; int o = rest % 3; int kk = rest / 3;
        dw2T[(kk * 3 + o) * 256 + i] = dw2[(kk * 256 + i) * 3 + o];
    }
    int v = t - (16384 + 12288);           // enorm[k] = ||emb[k]||^2
    if (v >= 0 && v < 2048) {
        const float* e = emb + v * 64;
        float s = 0.f;
        #pragma unroll
        for (int h = 0; h < 64; ++h) s += e[h] * e[h];
        enorm[v] = s;
    }
}

// ---------------------------------------------------------------- pack bf16 MFMA weight fragments
// w2p[t]: t = ((tap*4+cc)*16+nsg)*512 + lane*8 + j  <- w2[(tap*128 + cc*32+(lane>>4)*8+j)*256 + nsg*16+(lane&15)]
// dw1p[u]: u = ((tap*2+cc)*16+nsg)*512 + lane*8 + j <- dw1[(tap*64 + cc*32+(lane>>4)*8+j)*256 + nsg*16+(lane&15)]
__global__ __launch_bounds__(256) void k_pack(const float* __restrict__ w2, const float* __restrict__ dw1,
                                              unsigned short* __restrict__ w2p, unsigned short* __restrict__ dw1p) {
    int t = blockIdx.x * 256 + threadIdx.x;
    if (t < 524288) {
        int j = t & 7, lane = (t >> 3) & 63, nsg = (t >> 9) & 15, cc = (t >> 13) & 3, tap = t >> 15;
        int c = cc * 32 + ((lane >> 4) << 3) + j;
        int oc = nsg * 16 + (lane & 15);
        w2p[t] = f2b(w2[(tap * 128 + c) * 256 + oc]);
    } else {
        int u = t - 524288;
        if (u < 262144) {
            int j = u & 7, lane = (u >> 3) & 63, nsg = (u >> 9) & 15, cc = (u >> 13) & 1, tap = u >> 14;
            int c = cc * 32 + ((lane >> 4) << 3) + j;
            int oc = nsg * 16 + (lane & 15);
            dw1p[u] = f2b(dw1[(tap * 64 + c) * 256 + oc]);
        }
    }
}

// ---------------------------------------------------------------- conv1: x[16,256,256,3] -> h1b bf16[16,128,128,128]
__global__ __launch_bounds__(128) void k_conv1(const float* __restrict__ x, const float* __restrict__ w1,
                                               const float* __restrict__ b1, unsigned short* __restrict__ h1b) {
    __shared__ float smem[120]; // [iy 4][ix 10][c 3]
    int bx = blockIdx.x;
    int xg = bx & 31, y = (bx >> 5) & 127, b = bx >> 12;
    int x0 = xg << 2;
    int tid = threadIdx.x;
    if (tid < 120) {
        int c = tid % 3, sp = tid / 3;
        int iy = sp / 10, ix = sp - iy * 10;
        int gy = 2 * y - 1 + iy, gx = 2 * x0 - 1 + ix;
        float v = 0.f;
        if ((unsigned)gy < 256u && (unsigned)gx < 256u)
            v = x[((b * 256 + gy) * 256 + gx) * 3 + c];
        smem[tid] = v;
    }
    __syncthreads();
    int o = tid;
    float a0 = 0.f, a1 = 0.f, a2 = 0.f, a3 = 0.f;
    #pragma unroll
    for (int ky = 0; ky < 4; ++ky)
        #pragma unroll
        for (int kx = 0; kx < 4; ++kx)
            #pragma unroll
            for (int c = 0; c < 3; ++c) {
                float wv = w1[((ky * 4 + kx) * 3 + c) * 128 + o];
                a0 += smem[(ky * 10 + kx + 0) * 3 + c] * wv;
                a1 += smem[(ky * 10 + kx + 2) * 3 + c] * wv;
                a2 += smem[(ky * 10 + kx + 4) * 3 + c] * wv;
                a3 += smem[(ky * 10 + kx + 6) * 3 + c] * wv;
            }
    float bb = b1[o];
    int ob = ((b * 128 + y) * 128 + x0) * 128 + o;
    h1b[ob]       = f2b(leaky(a0 + bb));
    h1b[ob + 128] = f2b(leaky(a1 + bb));
    h1b[ob + 256] = f2b(leaky(a2 + bb));
    h1b[ob + 384] = f2b(leaky(a3 + bb));
}

// ---------------------------------------------------------------- conv2 MFMA: h1b -> h2 fp32[16,64,64,256]
// Block = (b, y0): one output row (64 px) x 256 oc. 4 waves x 64 oc. No LDS, no barriers.
__global__ __launch_bounds__(256) void k_conv2(const unsigned short* __restrict__ h1b,
                                               const unsigned short* __restrict__ w2p,
                                               const float* __restrict__ b2, float* __restrict__ h2) {
    int bx = blockIdx.x;
    int y0 = bx & 63, b = bx >> 6;
    int tid = threadIdx.x;
    int wave = tid >> 6, lane = tid & 63;
    int lr = lane & 15, lk = lane >> 4;
    f32x4 acc[4][4];
    #pragma unroll
    for (int i = 0; i < 4; ++i)
        #pragma unroll
        for (int j = 0; j < 4; ++j) acc[i][j] = (f32x4){0.f, 0.f, 0.f, 0.f};

    const unsigned short* hbase = h1b + (size_t)b * (128 * 128 * 128);
    #pragma unroll 1
    for (int tap = 0; tap < 16; ++tap) {
        int ky = tap >> 2, kx = tap & 3;
        int gy = 2 * y0 + ky - 1;
        bool rowok = (unsigned)gy < 128u;
        const unsigned short* rowp = hbase + gy * (128 * 128);
        int gxl = 2 * lr + kx - 1;
        #pragma unroll
        for (int cc = 0; cc < 4; ++cc) {
            int c0 = cc * 32 + lk * 8;
            s16x8 aF[4];
            #pragma unroll
            for (int ms = 0; ms < 4; ++ms) {
                int gx = gxl + ms * 32;
                aF[ms] = ldz(rowp + gx * 128 + c0, rowok && (unsigned)gx < 128u);
            }
            const unsigned short* wp = w2p + (((tap * 4 + cc) * 16 + wave * 4) * 64 + lane) * 8;
            s16x8 bF[4];
            #pragma unroll
            for (int ns = 0; ns < 4; ++ns) bF[ns] = *(const s16x8*)(wp + ns * 512);
            #pragma unroll
            for (int ms = 0; ms < 4; ++ms)
                #pragma unroll
                for (int ns = 0; ns < 4; ++ns)
                    acc[ms][ns] = __builtin_amdgcn_mfma_f32_16x16x32_bf16(aF[ms], bF[ns], acc[ms][ns], 0, 0, 0);
        }
    }
    int ocb = wave * 64;
    float* outp = h2 + ((size_t)(b * 64 + y0)) * 64 * 256;
    #pragma unroll
    for (int ns = 0; ns < 4; ++ns) {
        float bb = b2[ocb + ns * 16 + lr];
        #pragma unroll
        for (int ms = 0; ms < 4; ++ms)
            #pragma unroll
            for (int r = 0; r < 4; ++r) {
                int px = ms * 16 + lk * 4 + r;
                outp[px * 256 + ocb + ns * 16 + lr] = leaky(acc[ms][ns][r] + bb);
            }
    }
}

// ---------------------------------------------------------------- conv3: 1x1, h2 -> enc fp32[16,64,64,64]
__global__ __launch_bounds__(256) void k_conv3(const float* __restrict__ h2, const float* __restrict__ w3T,
                                               const float* __restrict__ b3, float* __restrict__ enc) {
    __shared__ float smem[1024];
    int bx = blockIdx.x;
    int tid = threadIdx.x;
    *(float4*)(smem + tid * 4) = LD4(h2 + bx * 1024 + tid * 4);
    __syncthreads();
    int p = tid >> 6, d = tid & 63;
    const float* wrow = w3T + d * 256;
    const float* in = smem + p * 256;
    float s0 = 0.f, s1 = 0.f, s2 = 0.f, s3 = 0.f;
    #pragma unroll 4
    for (int c = 0; c < 256; c += 4) {
        float4 iv = LD4(in + c);
        float4 wv = LD4(wrow + c);
        s0 += iv.x * wv.x; s1 += iv.y * wv.y; s2 += iv.z * wv.z; s3 += iv.w * wv.w;
    }
    enc[bx * 256 + tid] = b3[d] + ((s0 + s1) + (s2 + s3));
}

// ---------------------------------------------------------------- fused VQ (fp32), writes qdec bf16
__global__ __launch_bounds__(256, 2) void k_vq(const float* __restrict__ enc, const float* __restrict__ emb,
                                               const float* __restrict__ enorm,
                                               unsigned short* __restrict__ qdec, float* __restrict__ loss) {
    __shared__ float f_lds[64 * 64];
    __shared__ float e_lds[128 * 64];
    __shared__ float en_sh[128];
    __shared__ float red_s[16 * 64];
    __shared__ int   red_k[16 * 64];
    __shared__ int   bk_sh[64];

    int rb = blockIdx.x;
    int b = rb >> 6, w = rb & 63;
    int tid = threadIdx.x;
    int cl = tid & 63, hg = tid >> 6;

    const float* encb = enc + b * 262144 + w * 64;
    #pragma unroll
    for (int hp = 0; hp < 16; ++hp) {
        int h = hp * 4 + hg;
        f_lds[cl * 64 + FSWZ(h, cl)] = encb[h * 4096 + cl];
    }

    int tr = tid & 15, tc = tid >> 4;
    float bestl[4]; int bkl[4];
    #pragma unroll
    for (int i = 0; i < 4; ++i) { bestl[i] = 3.4e38f; bkl[i] = 0; }

    for (int ch = 0; ch < 16; ++ch) {
        __syncthreads();
        const float* eb = emb + ch * 8192;
        #pragma unroll
        for (int j = 0; j < 32; ++j) {
            int l = j * 256 + tid;
            int k = l >> 6, h = l & 63;
            e_lds[k * 64 + ESWZ(h, k)] = eb[l];
        }
        if (tid < 128) en_sh[tid] = enorm[ch * 128 + tid];
        __syncthreads();

        float accv[4][8];
        #pragma unroll
        for (int i = 0; i < 4; ++i)
            #pragma unroll
            for (int j = 0; j < 8; ++j) accv[i][j] = 0.f;

        #pragma unroll
        for (int h4 = 0; h4 < 16; ++h4) {
            float4 fv[4];
            #pragma unroll
            for (int i = 0; i < 4; ++i)
                fv[i] = LD4(f_lds + (tr * 4 + i) * 64 + ((h4 ^ tr) << 2));
            #pragma unroll
            for (int j = 0; j < 8; ++j) {
                int k = tc * 8 + j;
                float4 ev = LD4(e_lds + k * 64 + ((h4 ^ ((k >> 1) & 15)) << 2));
                #pragma unroll
                for (int i = 0; i < 4; ++i)
                    accv[i][j] += fv[i].x * ev.x + fv[i].y * ev.y + fv[i].z * ev.z + fv[i].w * ev.w;
            }
        }
        #pragma unroll
        for (int j = 0; j < 8; ++j) {
            float en = en_sh[tc * 8 + j];
            int kg = ch * 128 + tc * 8 + j;
            #pragma unroll
            for (int i = 0; i < 4; ++i) {
                float s = en - 2.f * accv[i][j];
                if (s < bestl[i]) { bestl[i] = s; bkl[i] = kg; }
            }
        }
    }

    #pragma unroll
    for (int i = 0; i < 4; ++i) {
        red_s[tc * 64 + tr * 4 + i] = bestl[i];
        red_k[tc * 64 + tr * 4 + i] = bkl[i];
    }
    __syncthreads();
    if (tid < 64) {
        float bs = red_s[tid]; int bk = red_k[tid];
        #pragma unroll
        for (int t = 1; t < 16; ++t) {
            float s = red_s[t * 64 + tid]; int k = red_k[t * 64 + tid];
            if (s < bs || (s == bs && k < bk)) { bs = s; bk = k; }
        }
        bk_sh[tid] = bk;
    }
    __syncthreads();

    int bk = bk_sh[cl];
    const float* ev = emb + bk * 64;
    unsigned short* qd = qdec + b * 262144 + w * 64 + cl;
    float ls = 0.f;
    #pragma unroll
    for (int hp = 0; hp < 16; ++hp) {
        int h = hp * 4 + hg;
        float e = ev[h];
        float f = f_lds[cl * 64 + FSWZ(h, cl)];
        float d = e - f;
        ls += d * d;
        qd[h * 4096] = f2b(e);
    }
    #pragma unroll
    for (int off = 32; off; off >>= 1) ls += __shfl_xor(ls, off, 64);
    if ((tid & 63) == 0) atomicAdd(loss, ls);
}

// ---------------------------------------------------------------- deconv1 MFMA: qdec bf16 -> g bf16[16,128,128,256]
// Block = (b, y, parx): 64 same-parity x of output row y, x = 2u+parx. 4 waves x 64 oc.
__global__ __launch_bounds__(256) void k_deconv1(const unsigned short* __restrict__ qdec,
                                                 const unsigned short* __restrict__ dw1p,
                                                 const float* __restrict__ db1, unsigned short* __restrict__ g) {
    int bx = blockIdx.x;
    int parx = bx & 1, y = (bx >> 1) & 127, b = bx >> 8;
    int pary = y & 1;
    int h0 = (y - 2 + pary) >> 1;
    int tid = threadIdx.x;
    int wave = tid >> 6, lane = tid & 63;
    int lr = lane & 15, lk = lane >> 4;
    f32x4 acc[4][4];
    #pragma unroll
    for (int i = 0; i < 4; ++i)
        #pragma unroll
        for (int j = 0; j < 4; ++j) acc[i][j] = (f32x4){0.f, 0.f, 0.f, 0.f};

    const unsigned short* qb = qdec + (size_t)b * (64 * 64 * 64);
    #pragma unroll
    for (int tky = 0; tky < 2; ++tky) {
        int h = h0 + tky;
        bool hok = (unsigned)h < 64u;
        const unsigned short* rowp = qb + h * (64 * 64);
        #pragma unroll
        for (int tkx = 0; tkx < 2; ++tkx) {
            int tap = (pary + 2 * tky) * 4 + parx + 2 * tkx;
            int wbase = lr + parx + tkx - 1;
            #pragma unroll
            for (int cc = 0; cc < 2; ++cc) {
                int c0 = cc * 32 + lk * 8;
                s16x8 aF[4];
                #pragma unroll
                for (int ms = 0; ms < 4; ++ms) {
                    int w = wbase + ms * 16;
                    aF[ms] = ldz(rowp + w * 64 + c0, hok && (unsigned)w < 64u);
                }
                const unsigned short* wp = dw1p + (((tap * 2 + cc) * 16 + wave * 4) * 64 + lane) * 8;
                s16x8 bF[4];
                #pragma unroll
                for (int ns = 0; ns < 4; ++ns) bF[ns] = *(const s16x8*)(wp + ns * 512);
                #pragma unroll
                for (int ms = 0; ms < 4; ++ms)
                    #pragma unroll
                    for (int ns = 0; ns < 4; ++ns)
                        acc[ms][ns] = __builtin_amdgcn_mfma_f32_16x16x32_bf16(aF[ms], bF[ns], acc[ms][ns], 0, 0, 0);
            }
        }
    }
    int ocb = wave * 64;
    unsigned short* gp = g + ((size_t)(b * 128 + y)) * 128 * 256;
    #pragma unroll
    for (int ns = 0; ns < 4; ++ns) {
        float bb = db1[ocb + ns * 16 + lr];
        #pragma unroll
        for (int ms = 0; ms < 4; ++ms)
            #pragma unroll
            for (int r = 0; r < 4; ++r) {
                int u = ms * 16 + lk * 4 + r;
                int xo = 2 * u + parx;
                gp[xo * 256 + ocb + ns * 16 + lr] = f2b(leaky(acc[ms][ns][r] + bb));
            }
    }
}

// ---------------------------------------------------------------- deconv2: g bf16 -> recon fp32, tanh; all 16 batches
__global__ __launch_bounds__(256) void k_deconv2(const unsigned short* __restrict__ g, const float* __restrict__ dw2T,
                                                 const float* __restrict__ db2, float* __restrict__ out,
                                                 const float* __restrict__ loss) {
    int p = blockIdx.x * 256 + threadIdx.x;   // 16*65536 pixels
    int x = p & 255, y = (p >> 8) & 255, b = p >> 16;
    float a0 = db2[0], a1 = db2[1], a2 = db2[2];
    #pragma unroll
    for (int tky = 0; tky < 2; ++tky) {
        int ky = (y & 1) + 2 * tky;
        int h = (y - 2 + ky) >> 1;
        if ((unsigned)h >= 128u) continue;
        #pragma unroll
        for (int tkx = 0; tkx < 2; ++tkx) {
            int kx = (x & 1) + 2 * tkx;
            int w = (x - 2 + kx) >> 1;
            if ((unsigned)w >= 128u) continue;
            const unsigned short* gb = g + (((size_t)b * 128 + h) * 128 + w) * 256;
            const float* wr = dw2T + (ky * 4 + kx) * 3 * 256;
            #pragma unroll 4
            for (int i = 0; i < 256; i += 4) {
                float g0 = b2f(gb[i]), g1 = b2f(gb[i + 1]), g2 = b2f(gb[i + 2]), g3 = b2f(gb[i + 3]);
                float4 wa = LD4(wr + i);
                float4 wb = LD4(wr + 256 + i);
                float4 wc = LD4(wr + 512 + i);
                a0 += g0 * wa.x + g1 * wa.y + g2 * wa.z + g3 * wa.w;
                a1 += g0 * wb.x + g1 * wb.y + g2 * wb.z + g3 * wb.w;
                a2 += g0 * wc.x + g1 * wc.y + g2 * wc.z + g3 * wc.w;
            }
        }
    }
    int ob = (b * 65536 + (y << 8) + x) * 3;
    out[ob]     = tanhf(a0);
    out[ob + 1] = tanhf(a1);
    out[ob + 2] = tanhf(a2);
    if (p == 0)
        out[3145728] = loss[0] * (1.25f / 4194304.f);
}

// ---------------------------------------------------------------- launch
extern "C" void kernel_launch(void* const* d_in, const int* in_sizes, int n_in,
                              void* d_out, int out_size, void* d_ws, size_t ws_size,
                              hipStream_t stream) {
    const float* x   = (const float*)d_in[0];
    const float* emb = (const float*)d_in[1];
    const float* w1  = (const float*)d_in[2];
    const float* b1  = (const float*)d_in[3];
    const float* w2  = (const float*)d_in[4];
    const float* b2  = (const float*)d_in[5];
    const float* w3  = (const float*)d_in[6];
    const float* b3  = (const float*)d_in[7];
    const float* dw1 = (const float*)d_in[8];
    const float* db1 = (const float*)d_in[9];
    const float* dw2 = (const float*)d_in[10];
    const float* db2 = (const float*)d_in[11];
    float* out = (float*)d_out;
    float* ws  = (float*)d_ws;

    if (ws_size < (size_t)57047056 * 4) return;

    unsigned short* h1b  = (unsigned short*)ws;            // bf16, overlapped with g
    unsigned short* g    = (unsigned short*)ws;            // bf16 [16,128,128,256]
    float* h2    = ws + 33554432;
    float* enc   = ws + 50331648;
    unsigned short* qdec = (unsigned short*)(ws + 54525952);
    float* w3T   = ws + 56623104;
    float* dw2T  = ws + 56639488;
    float* enorm = ws + 56651776;
    float* loss  = ws + 56653824;
    unsigned short* w2p  = (unsigned short*)(ws + 56653840);
    unsigned short* dw1p = (unsigned short*)(ws + 56915984);

    k_prep   <<<120,   256, 0, stream>>>(w3, dw2, emb, w3T, dw2T, enorm, loss);
    k_pack   <<<3072,  256, 0, stream>>>(w2, dw1, w2p, dw1p);
    k_conv1  <<<65536, 128, 0, stream>>>(x, w1, b1, h1b);
    k_conv2  <<<1024,  256, 0, stream>>>(h1b, w2p, b2, h2);
    k_conv3  <<<16384, 256, 0, stream>>>(h2, w3T, b3, enc);
    k_vq     <<<1024,  256, 0, stream>>>(enc, emb, enorm, qdec, loss);
    k_deconv1<<<4096,  256, 0, stream>>>(qdec, dw1p, db1, g);
    k_deconv2<<<4096,  256, 0, stream>>>(g, dw2T, db2, out, loss);
}

// Round 4
// 1063.105 us; speedup vs baseline: 3.9319x; 1.9551x over previous
//
#include <hip/hip_runtime.h>
#include <math.h>

// VQ-VAE forward. MI355X / gfx950. bf16-MFMA conv2(+fused conv3), deconv1, deconv2.
// prep -> pack -> conv1(bf16 out) -> conv2+3(MFMA, enc out) -> vq -> deconv1(MFMA) -> deconv2(MFMA)
// Workspace (float slots):
//   [0)          h1b bf16 (33.5M elems = 16,777,216 slots); later g bf16 (67.1M elems = 33,554,432 slots)
//   [33554432)   enc fp32  4,194,304
//   [37748736)   qdec bf16 (4.2M elems = 2,097,152 slots)
//   [39845888)   enorm     2,048
//   [39847936)   loss      16
//   [39847952)   w2p  bf16 524,288 elems (262,144 slots)
//   [40110096)   dw1p bf16 262,144 elems (131,072 slots)
//   [40241168)   w3p  bf16  16,384 elems (8,192 slots)
//   [40249360)   dwp  bf16  65,536 elems (32,768 slots)
//   total 40,282,128 floats = 161.1 MB

typedef short s16x8 __attribute__((ext_vector_type(8)));
typedef float f32x4 __attribute__((ext_vector_type(4)));

#define LD4(p) (*(const float4*)(p))

__device__ __forceinline__ float leaky(float v) { return v >= 0.f ? v : 0.01f * v; }
__device__ __forceinline__ unsigned short f2b(float f) {
    union { float f; unsigned u; } v; v.f = f;
    unsigned r = v.u + 0x7fffu + ((v.u >> 16) & 1u);
    return (unsigned short)(r >> 16);
}
__device__ __forceinline__ s16x8 ldz(const unsigned short* p, bool ok) {
    s16x8 z = {0,0,0,0,0,0,0,0};
    return ok ? *(const s16x8*)p : z;
}

// swizzles for VQ LDS
#define FSWZ(h, c) ((((((h) >> 2) ^ (((c) >> 2) & 15)) << 2)) | ((h) & 3))
#define ESWZ(h, k) ((((((h) >> 2) ^ (((k) >> 1) & 15)) << 2)) | ((h) & 3))

// ---------------------------------------------------------------- prep: enorm + loss init
__global__ __launch_bounds__(256) void k_prep(const float* __restrict__ emb,
                                              float* __restrict__ enorm, float* __restrict__ loss) {
    int t = blockIdx.x * 256 + threadIdx.x;
    if (t == 0) loss[0] = 0.f;
    if (t < 2048) {
        const float* e = emb + t * 64;
        float s = 0.f;
        #pragma unroll
        for (int h = 0; h < 64; ++h) s += e[h] * e[h];
        enorm[t] = s;
    }
}

// ---------------------------------------------------------------- pack bf16 MFMA fragments
// w2p : ((tap*4+cc)*16+nsg)*512 + lane*8 + j <- w2[(tap*128 + cc*32+(lane>>4)*8+j)*256 + nsg*16+(lane&15)]
// dw1p: ((tap*2+cc)*16+nsg)*512 + lane*8 + j <- dw1[(tap*64  + cc*32+(lane>>4)*8+j)*256 + nsg*16+(lane&15)]
// w3p : (wave*8+ks)*512 + lane*8 + j         <- w3[(ks*32+(lane>>4)*8+j)*64 + wave*16+(lane&15)]
// dwp : (par*32+ks)*512 + lane*8 + j         <- dw2[((ky*4+kx)*256 + c)*3 + oc], k=ks*32+(lane>>4)*8+j
__global__ __launch_bounds__(256) void k_pack(const float* __restrict__ w2, const float* __restrict__ dw1,
                                              const float* __restrict__ w3, const float* __restrict__ dw2,
                                              unsigned short* __restrict__ w2p, unsigned short* __restrict__ dw1p,
                                              unsigned short* __restrict__ w3p, unsigned short* __restrict__ dwp) {
    int t = blockIdx.x * 256 + threadIdx.x;
    if (t < 524288) {
        int j = t & 7, lane = (t >> 3) & 63, nsg = (t >> 9) & 15, cc = (t >> 13) & 3, tap = t >> 15;
        int c = cc * 32 + ((lane >> 4) << 3) + j;
        int oc = nsg * 16 + (lane & 15);
        w2p[t] = f2b(w2[(tap * 128 + c) * 256 + oc]);
    } else if (t < 786432) {
        int u = t - 524288;
        int j = u & 7, lane = (u >> 3) & 63, nsg = (u >> 9) & 15, cc = (u >> 13) & 1, tap = u >> 14;
        int c = cc * 32 + ((lane >> 4) << 3) + j;
        int oc = nsg * 16 + (lane & 15);
        dw1p[u] = f2b(dw1[(tap * 64 + c) * 256 + oc]);
    } else if (t < 802816) {
        int v = t - 786432;
        int j = v & 7, lane = (v >> 3) & 63, ks = (v >> 9) & 7, wv = v >> 12;
        int c = ks * 32 + ((lane >> 4) << 3) + j;
        int d = wv * 16 + (lane & 15);
        w3p[v] = f2b(w3[c * 64 + d]);
    } else {
        int u2 = t - 802816;  // 65536
        int j = u2 & 7, lane = (u2 >> 3) & 63, ks = (u2 >> 9) & 31, par = u2 >> 14;
        int py = par >> 1, px0 = par & 1;
        int k = ks * 32 + ((lane >> 4) << 3) + j;
        int tap = k >> 8, c = k & 255;
        int ky = py + 2 * (tap >> 1), kx = px0 + 2 * (tap & 1);
        int oc = lane & 15;
        dwp[u2] = (oc < 3) ? f2b(dw2[((ky * 4 + kx) * 256 + c) * 3 + oc]) : (unsigned short)0;
    }
}

// ---------------------------------------------------------------- conv1: x[16,256,256,3] -> h1b bf16[16,128,128,128]
__global__ __launch_bounds__(128) void k_conv1(const float* __restrict__ x, const float* __restrict__ w1,
                                               const float* __restrict__ b1, unsigned short* __restrict__ h1b) {
    __shared__ float smem[120]; // [iy 4][ix 10][c 3]
    int bx = blockIdx.x;
    int xg = bx & 31, y = (bx >> 5) & 127, b = bx >> 12;
    int x0 = xg << 2;
    int tid = threadIdx.x;
    if (tid < 120) {
        int c = tid % 3, sp = tid / 3;
        int iy = sp / 10, ix = sp - iy * 10;
        int gy = 2 * y - 1 + iy, gx = 2 * x0 - 1 + ix;
        float v = 0.f;
        if ((unsigned)gy < 256u && (unsigned)gx < 256u)
            v = x[((b * 256 + gy) * 256 + gx) * 3 + c];
        smem[tid] = v;
    }
    __syncthreads();
    int o = tid;
    float a0 = 0.f, a1 = 0.f, a2 = 0.f, a3 = 0.f;
    #pragma unroll
    for (int ky = 0; ky < 4; ++ky)
        #pragma unroll
        for (int kx = 0; kx < 4; ++kx)
            #pragma unroll
            for (int c = 0; c < 3; ++c) {
                float wv = w1[((ky * 4 + kx) * 3 + c) * 128 + o];
                a0 += smem[(ky * 10 + kx + 0) * 3 + c] * wv;
                a1 += smem[(ky * 10 + kx + 2) * 3 + c] * wv;
                a2 += smem[(ky * 10 + kx + 4) * 3 + c] * wv;
                a3 += smem[(ky * 10 + kx + 6) * 3 + c] * wv;
            }
    float bb = b1[o];
    int ob = ((b * 128 + y) * 128 + x0) * 128 + o;
    h1b[ob]       = f2b(leaky(a0 + bb));
    h1b[ob + 128] = f2b(leaky(a1 + bb));
    h1b[ob + 256] = f2b(leaky(a2 + bb));
    h1b[ob + 384] = f2b(leaky(a3 + bb));
}

// ---------------------------------------------------------------- conv2 MFMA + fused conv3: h1b -> enc fp32[16,64,64,64]
// Block = (b, y0): one output row (64 px) x 256 oc. 4 waves x 64 oc. Then 1x1 conv3 via LDS handoff.
__global__ __launch_bounds__(256) void k_conv2(const unsigned short* __restrict__ h1b,
                                               const unsigned short* __restrict__ w2p,
                                               const float* __restrict__ b2,
                                               const unsigned short* __restrict__ w3p,
                                               const float* __restrict__ b3,
                                               float* __restrict__ enc) {
    __shared__ unsigned short h2s[64 * 256];   // [px][c] bf16, XOR-swizzled in 8-elem groups
    int bx = blockIdx.x;
    int y0 = bx & 63, b = bx >> 6;
    int tid = threadIdx.x;
    int wv = tid >> 6, lane = tid & 63;
    int lr = lane & 15, lk = lane >> 4;
    f32x4 acc[4][4];
    #pragma unroll
    for (int i = 0; i < 4; ++i)
        #pragma unroll
        for (int j = 0; j < 4; ++j) acc[i][j] = (f32x4){0.f, 0.f, 0.f, 0.f};

    const unsigned short* hbase = h1b + (size_t)b * (128 * 128 * 128);
    #pragma unroll 1
    for (int tap = 0; tap < 16; ++tap) {
        int ky = tap >> 2, kx = tap & 3;
        int gy = 2 * y0 + ky - 1;
        bool rowok = (unsigned)gy < 128u;
        const unsigned short* rowp = hbase + gy * (128 * 128);
        int gxl = 2 * lr + kx - 1;
        #pragma unroll
        for (int cc = 0; cc < 4; ++cc) {
            int c0 = cc * 32 + lk * 8;
            s16x8 aF[4];
            #pragma unroll
            for (int ms = 0; ms < 4; ++ms) {
                int gx = gxl + ms * 32;
                aF[ms] = ldz(rowp + gx * 128 + c0, rowok && (unsigned)gx < 128u);
            }
            const unsigned short* wp = w2p + (((tap * 4 + cc) * 16 + wv * 4) * 64 + lane) * 8;
            s16x8 bF[4];
            #pragma unroll
            for (int ns = 0; ns < 4; ++ns) bF[ns] = *(const s16x8*)(wp + ns * 512);
            #pragma unroll
            for (int ms = 0; ms < 4; ++ms)
                #pragma unroll
                for (int ns = 0; ns < 4; ++ns)
                    acc[ms][ns] = __builtin_amdgcn_mfma_f32_16x16x32_bf16(aF[ms], bF[ns], acc[ms][ns], 0, 0, 0);
        }
    }
    // epilogue 1: bias + leaky -> bf16 LDS tile (swizzled)
    int ocb = wv * 64;
    #pragma unroll
    for (int ns = 0; ns < 4; ++ns) {
        int c = ocb + ns * 16 + lr;
        float bb = b2[c];
        int cg = c >> 3, cj = c & 7;
        #pragma unroll
        for (int ms = 0; ms < 4; ++ms)
            #pragma unroll
            for (int r = 0; r < 4; ++r) {
                int px = ms * 16 + lk * 4 + r;
                h2s[px * 256 + ((cg ^ (px & 31)) << 3) + cj] = f2b(leaky(acc[ms][ns][r] + bb));
            }
    }
    __syncthreads();
    // conv3: 64px x 64d, K=256. Wave wv covers d = wv*16 + (0..15).
    f32x4 a3[4];
    #pragma unroll
    for (int i = 0; i < 4; ++i) a3[i] = (f32x4){0.f, 0.f, 0.f, 0.f};
    #pragma unroll
    for (int ks = 0; ks < 8; ++ks) {
        s16x8 bF = *(const s16x8*)(w3p + ((wv * 8 + ks) * 64 + lane) * 8);
        int cg = ks * 4 + lk;
        #pragma unroll
        for (int ms = 0; ms < 4; ++ms) {
            int px = lr + ms * 16;
            s16x8 aF = *(const s16x8*)(h2s + px * 256 + ((cg ^ (px & 31)) << 3));
            a3[ms] = __builtin_amdgcn_mfma_f32_16x16x32_bf16(aF, bF, a3[ms], 0, 0, 0);
        }
    }
    float bb3 = b3[wv * 16 + lr];
    float* outp = enc + ((size_t)(b * 64 + y0)) * 64 * 64;
    #pragma unroll
    for (int ms = 0; ms < 4; ++ms)
        #pragma unroll
        for (int r = 0; r < 4; ++r) {
            int px = ms * 16 + lk * 4 + r;
            outp[px * 64 + wv * 16 + lr] = a3[ms][r] + bb3;
        }
}

// ---------------------------------------------------------------- fused VQ (fp32), writes qdec bf16
__global__ __launch_bounds__(256, 2) void k_vq(const float* __restrict__ enc, const float* __restrict__ emb,
                                               const float* __restrict__ enorm,
                                               unsigned short* __restrict__ qdec, float* __restrict__ loss) {
    __shared__ float f_lds[64 * 64];
    __shared__ float e_lds[128 * 64];
    __shared__ float en_sh[128];
    __shared__ float red_s[16 * 64];
    __shared__ int   red_k[16 * 64];
    __shared__ int   bk_sh[64];

    int rb = blockIdx.x;
    int b = rb >> 6, w = rb & 63;
    int tid = threadIdx.x;
    int cl = tid & 63, hg = tid >> 6;

    const float* encb = enc + b * 262144 + w * 64;
    #pragma unroll
    for (int hp = 0; hp < 16; ++hp) {
        int h = hp * 4 + hg;
        f_lds[cl * 64 + FSWZ(h, cl)] = encb[h * 4096 + cl];
    }

    int tr = tid & 15, tc = tid >> 4;
    float bestl[4]; int bkl[4];
    #pragma unroll
    for (int i = 0; i < 4; ++i) { bestl[i] = 3.4e38f; bkl[i] = 0; }

    for (int ch = 0; ch < 16; ++ch) {
        __syncthreads();
        const float* eb = emb + ch * 8192;
        #pragma unroll
        for (int j = 0; j < 32; ++j) {
            int l = j * 256 + tid;
            int k = l >> 6, h = l & 63;
            e_lds[k * 64 + ESWZ(h, k)] = eb[l];
        }
        if (tid < 128) en_sh[tid] = enorm[ch * 128 + tid];
        __syncthreads();

        float accv[4][8];
        #pragma unroll
        for (int i = 0; i < 4; ++i)
            #pragma unroll
            for (int j = 0; j < 8; ++j) accv[i][j] = 0.f;

        #pragma unroll
        for (int h4 = 0; h4 < 16; ++h4) {
            float4 fv[4];
            #pragma unroll
            for (int i = 0; i < 4; ++i)
                fv[i] = LD4(f_lds + (tr * 4 + i) * 64 + ((h4 ^ tr) << 2));
            #pragma unroll
            for (int j = 0; j < 8; ++j) {
                int k = tc * 8 + j;
                float4 ev = LD4(e_lds + k * 64 + ((h4 ^ ((k >> 1) & 15)) << 2));
                #pragma unroll
                for (int i = 0; i < 4; ++i)
                    accv[i][j] += fv[i].x * ev.x + fv[i].y * ev.y + fv[i].z * ev.z + fv[i].w * ev.w;
            }
        }
        #pragma unroll
        for (int j = 0; j < 8; ++j) {
            float en = en_sh[tc * 8 + j];
            int kg = ch * 128 + tc * 8 + j;
            #pragma unroll
            for (int i = 0; i < 4; ++i) {
                float s = en - 2.f * accv[i][j];
                if (s < bestl[i]) { bestl[i] = s; bkl[i] = kg; }
            }
        }
    }

    #pragma unroll
    for (int i = 0; i < 4; ++i) {
        red_s[tc * 64 + tr * 4 + i] = bestl[i];
        red_k[tc * 64 + tr * 4 + i] = bkl[i];
    }
    __syncthreads();
    if (tid < 64) {
        float bs = red_s[tid]; int bk = red_k[tid];
        #pragma unroll
        for (int t = 1; t < 16; ++t) {
            float s = red_s[t * 64 + tid]; int k = red_k[t * 64 + tid];
            if (s < bs || (s == bs && k < bk)) { bs = s; bk = k; }
        }
        bk_sh[tid] = bk;
    }
    __syncthreads();

    int bk = bk_sh[cl];
    const float* ev = emb + bk * 64;
    unsigned short* qd = qdec + b * 262144 + w * 64 + cl;
    float ls = 0.f;
    #pragma unroll
    for (int hp = 0; hp < 16; ++hp) {
        int h = hp * 4 + hg;
        float e = ev[h];
        float f = f_lds[cl * 64 + FSWZ(h, cl)];
        float d = e - f;
        ls += d * d;
        qd[h * 4096] = f2b(e);
    }
    #pragma unroll
    for (int off = 32; off; off >>= 1) ls += __shfl_xor(ls, off, 64);
    if ((tid & 63) == 0) atomicAdd(loss, ls);
}

// ---------------------------------------------------------------- deconv1 MFMA: qdec bf16 -> g bf16[16,128,128,256]
__global__ __launch_bounds__(256) void k_deconv1(const unsigned short* __restrict__ qdec,
                                                 const unsigned short* __restrict__ dw1p,
                                                 const float* __restrict__ db1, unsigned short* __restrict__ g) {
    int bx = blockIdx.x;
    int parx = bx & 1, y = (bx >> 1) & 127, b = bx >> 8;
    int pary = y & 1;
    int h0 = (y - 2 + pary) >> 1;
    int tid = threadIdx.x;
    int wv = tid >> 6, lane = tid & 63;
    int lr = lane & 15, lk = lane >> 4;
    f32x4 acc[4][4];
    #pragma unroll
    for (int i = 0; i < 4; ++i)
        #pragma unroll
        for (int j = 0; j < 4; ++j) acc[i][j] = (f32x4){0.f, 0.f, 0.f, 0.f};

    const unsigned short* qb = qdec + (size_t)b * (64 * 64 * 64);
    #pragma unroll
    for (int tky = 0; tky < 2; ++tky) {
        int h = h0 + tky;
        bool hok = (unsigned)h < 64u;
        const unsigned short* rowp = qb + h * (64 * 64);
        #pragma unroll
        for (int tkx = 0; tkx < 2; ++tkx) {
            int tap = (pary + 2 * tky) * 4 + parx + 2 * tkx;
            int wbase = lr + parx + tkx - 1;
            #pragma unroll
            for (int cc = 0; cc < 2; ++cc) {
                int c0 = cc * 32 + lk * 8;
                s16x8 aF[4];
                #pragma unroll
                for (int ms = 0; ms < 4; ++ms) {
                    int w = wbase + ms * 16;
                    aF[ms] = ldz(rowp + w * 64 + c0, hok && (unsigned)w < 64u);
                }
                const unsigned short* wp = dw1p + (((tap * 2 + cc) * 16 + wv * 4) * 64 + lane) * 8;
                s16x8 bF[4];
                #pragma unroll
                for (int ns = 0; ns < 4; ++ns) bF[ns] = *(const s16x8*)(wp + ns * 512);
                #pragma unroll
                for (int ms = 0; ms < 4; ++ms)
                    #pragma unroll
                    for (int ns = 0; ns < 4; ++ns)
                        acc[ms][ns] = __builtin_amdgcn_mfma_f32_16x16x32_bf16(aF[ms], bF[ns], acc[ms][ns], 0, 0, 0);
            }
        }
    }
    int ocb = wv * 64;
    unsigned short* gp = g + ((size_t)(b * 128 + y)) * 128 * 256;
    #pragma unroll
    for (int ns = 0; ns < 4; ++ns) {
        float bb = db1[ocb + ns * 16 + lr];
        #pragma unroll
        for (int ms = 0; ms < 4; ++ms)
            #pragma unroll
            for (int r = 0; r < 4; ++r) {
                int u = ms * 16 + lk * 4 + r;
                int xo = 2 * u + parx;
                gp[xo * 256 + ocb + ns * 16 + lr] = f2b(leaky(acc[ms][ns][r] + bb));
            }
    }
}

// ---------------------------------------------------------------- deconv2 MFMA: g bf16 -> recon fp32[16,256,256,3], tanh
// Block = (b, y) XCD-chunk-swizzled. Wave: px0 = wv>>1 (x parity), half = wv&1 (x half).
// M = 64 n-positions (x = 2n+px0), N = 16 (3 oc used), K = 4 taps x 256 ch = 1024.
__global__ __launch_bounds__(256) void k_deconv2(const unsigned short* __restrict__ g,
                                                 const unsigned short* __restrict__ dwp,
                                                 const float* __restrict__ db2, float* __restrict__ out,
                                                 const float* __restrict__ loss) {
    int bx = blockIdx.x;
    int swz = (bx & 7) * 512 + (bx >> 3);     // XCD-chunked: each XCD walks contiguous (b,y)
    int b = swz >> 8, y = swz & 255;
    int tid = threadIdx.x;
    int wv = tid >> 6, lane = tid & 63;
    int lr = lane & 15, lk = lane >> 4;
    int px0 = wv >> 1, half = wv & 1;
    int py = y & 1;
    int h0 = (y - 2 + py) >> 1;

    f32x4 acc[4];
    #pragma unroll
    for (int i = 0; i < 4; ++i) acc[i] = (f32x4){0.f, 0.f, 0.f, 0.f};

    const unsigned short* dwb = dwp + (size_t)(py * 2 + px0) * 32 * 512;
    const unsigned short* gb = g + (size_t)b * (128 * 128 * 256);

    #pragma unroll
    for (int tap = 0; tap < 4; ++tap) {
        int tky = tap >> 1, tkx = tap & 1;
        int h = h0 + tky;
        bool hok = (unsigned)h < 128u;
        const unsigned short* rowp = gb + h * (128 * 256);
        int wofs = px0 - 1 + tkx;
        #pragma unroll
        for (int k8 = 0; k8 < 8; ++k8) {
            int ks = tap * 8 + k8;
            int c0 = k8 * 32 + lk * 8;
            s16x8 bF = *(const s16x8*)(dwb + (ks * 64 + lane) * 8);
            #pragma unroll
            for (int ms = 0; ms < 4; ++ms) {
                int n = half * 64 + ms * 16 + lr;
                int w = n + wofs;
                s16x8 aF = ldz(rowp + w * 256 + c0, hok && (unsigned)w < 128u);
                acc[ms] = __builtin_amdgcn_mfma_f32_16x16x32_bf16(aF, bF, acc[ms], 0, 0, 0);
            }
        }
    }
    if (lr < 3) {
        float bb = db2[lr];
        #pragma unroll
        for (int ms = 0; ms < 4; ++ms)
            #pragma unroll
            for (int r = 0; r < 4; ++r) {
                int n = half * 64 + ms * 16 + lk * 4 + r;
                int x = 2 * n + px0;
                out[((size_t)b * 65536 + y * 256 + x) * 3 + lr] = tanhf(acc[ms][r] + bb);
            }
    }
    if (bx == 0 && tid == 0)
        out[3145728] = loss[0] * (1.25f / 4194304.f);
}

// ---------------------------------------------------------------- launch
extern "C" void kernel_launch(void* const* d_in, const int* in_sizes, int n_in,
                              void* d_out, int out_size, void* d_ws, size_t ws_size,
                              hipStream_t stream) {
    const float* x   = (const float*)d_in[0];
    const float* emb = (const float*)d_in[1];
    const float* w1  = (const float*)d_in[2];
    const float* b1  = (const float*)d_in[3];
    const float* w2  = (const float*)d_in[4];
    const float* b2  = (const float*)d_in[5];
    const float* w3  = (const float*)d_in[6];
    const float* b3  = (const float*)d_in[7];
    const float* dw1 = (const float*)d_in[8];
    const float* db1 = (const float*)d_in[9];
    const float* dw2 = (const float*)d_in[10];
    const float* db2 = (const float*)d_in[11];
    float* out = (float*)d_out;
    float* ws  = (float*)d_ws;

    if (ws_size < (size_t)40282128 * 4) return;

    unsigned short* h1b  = (unsigned short*)ws;            // bf16, later overlapped by g
    unsigned short* g    = (unsigned short*)ws;            // bf16 [16,128,128,256]
    float* enc   = ws + 33554432;
    unsigned short* qdec = (unsigned short*)(ws + 37748736);
    float* enorm = ws + 39845888;
    float* loss  = ws + 39847936;
    unsigned short* w2p  = (unsigned short*)(ws + 39847952);
    unsigned short* dw1p = (unsigned short*)(ws + 40110096);
    unsigned short* w3p  = (unsigned short*)(ws + 40241168);
    unsigned short* dwp  = (unsigned short*)(ws + 40249360);

    k_prep   <<<8,     256, 0, stream>>>(emb, enorm, loss);
    k_pack   <<<3392,  256, 0, stream>>>(w2, dw1, w3, dw2, w2p, dw1p, w3p, dwp);
    k_conv1  <<<65536, 128, 0, stream>>>(x, w1, b1, h1b);
    k_conv2  <<<1024,  256, 0, stream>>>(h1b, w2p, b2, w3p, b3, enc);
    k_vq     <<<1024,  256, 0, stream>>>(enc, emb, enorm, qdec, loss);
    k_deconv1<<<4096,  256, 0, stream>>>(qdec, dw1p, db1, g);
    k_deconv2<<<4096,  256, 0, stream>>>(g, dwp, db2, out, loss);
}

// Round 5
// 765.593 us; speedup vs baseline: 5.4598x; 1.3886x over previous
//
#include <hip/hip_runtime.h>
#include <math.h>

// VQ-VAE forward. MI355X / gfx950. bf16-MFMA conv2(+fused conv3), vq-distance, deconv1, deconv2.
// prep -> pack -> conv1(bf16 out) -> conv2+3(MFMA, enc out) -> vq(MFMA) -> deconv1(MFMA) -> deconv2(MFMA)
// Workspace (float slots):
//   [0)          h1b bf16 (33.5M elems = 16,777,216 slots); later g bf16 (67.1M elems = 33,554,432 slots)
//   [33554432)   enc fp32  4,194,304
//   [37748736)   qdec bf16 (4.2M elems = 2,097,152 slots)
//   [39845888)   enorm     2,048
//   [39847936)   loss      16
//   [39847952)   w2p  bf16 524,288 elems (262,144 slots)
//   [40110096)   dw1p bf16 262,144 elems (131,072 slots)
//   [40241168)   w3p  bf16  16,384 elems (8,192 slots)
//   [40249360)   dwp  bf16  65,536 elems (32,768 slots)
//   [40282128)   ebp  bf16 131,072 elems (65,536 slots)   = bf16(-2*emb)
//   total 40,347,664 floats = 161.4 MB

typedef short s16x8 __attribute__((ext_vector_type(8)));
typedef float f32x4 __attribute__((ext_vector_type(4)));

#define LD4(p) (*(const float4*)(p))

__device__ __forceinline__ float leaky(float v) { return v >= 0.f ? v : 0.01f * v; }
__device__ __forceinline__ unsigned short f2b(float f) {
    union { float f; unsigned u; } v; v.f = f;
    unsigned r = v.u + 0x7fffu + ((v.u >> 16) & 1u);
    return (unsigned short)(r >> 16);
}
__device__ __forceinline__ s16x8 ldz(const unsigned short* p, bool ok) {
    s16x8 z = {0,0,0,0,0,0,0,0};
    return ok ? *(const s16x8*)p : z;
}

// ---------------------------------------------------------------- prep: enorm + ebp(-2e bf16) + loss init
__global__ __launch_bounds__(256) void k_prep(const float* __restrict__ emb,
                                              float* __restrict__ enorm, float* __restrict__ loss,
                                              unsigned short* __restrict__ ebp) {
    int t = blockIdx.x * 256 + threadIdx.x;
    if (t == 0) loss[0] = 0.f;
    if (t < 2048) {
        const float* e = emb + t * 64;
        float s = 0.f;
        #pragma unroll
        for (int h = 0; h < 64; ++h) {
            float ev = e[h];
            s += ev * ev;
            ebp[t * 64 + h] = f2b(-2.f * ev);
        }
        enorm[t] = s;
    }
}

// ---------------------------------------------------------------- pack bf16 MFMA fragments
__global__ __launch_bounds__(256) void k_pack(const float* __restrict__ w2, const float* __restrict__ dw1,
                                              const float* __restrict__ w3, const float* __restrict__ dw2,
                                              unsigned short* __restrict__ w2p, unsigned short* __restrict__ dw1p,
                                              unsigned short* __restrict__ w3p, unsigned short* __restrict__ dwp) {
    int t = blockIdx.x * 256 + threadIdx.x;
    if (t < 524288) {
        int j = t & 7, lane = (t >> 3) & 63, nsg = (t >> 9) & 15, cc = (t >> 13) & 3, tap = t >> 15;
        int c = cc * 32 + ((lane >> 4) << 3) + j;
        int oc = nsg * 16 + (lane & 15);
        w2p[t] = f2b(w2[(tap * 128 + c) * 256 + oc]);
    } else if (t < 786432) {
        int u = t - 524288;
        int j = u & 7, lane = (u >> 3) & 63, nsg = (u >> 9) & 15, cc = (u >> 13) & 1, tap = u >> 14;
        int c = cc * 32 + ((lane >> 4) << 3) + j;
        int oc = nsg * 16 + (lane & 15);
        dw1p[u] = f2b(dw1[(tap * 64 + c) * 256 + oc]);
    } else if (t < 802816) {
        int v = t - 786432;
        int j = v & 7, lane = (v >> 3) & 63, ks = (v >> 9) & 7, wv = v >> 12;
        int c = ks * 32 + ((lane >> 4) << 3) + j;
        int d = wv * 16 + (lane & 15);
        w3p[v] = f2b(w3[c * 64 + d]);
    } else {
        int u2 = t - 802816;  // 65536
        int j = u2 & 7, lane = (u2 >> 3) & 63, ks = (u2 >> 9) & 31, par = u2 >> 14;
        int py = par >> 1, px0 = par & 1;
        int k = ks * 32 + ((lane >> 4) << 3) + j;
        int tap = k >> 8, c = k & 255;
        int ky = py + 2 * (tap >> 1), kx = px0 + 2 * (tap & 1);
        int oc = lane & 15;
        dwp[u2] = (oc < 3) ? f2b(dw2[((ky * 4 + kx) * 256 + c) * 3 + oc]) : (unsigned short)0;
    }
}

// ---------------------------------------------------------------- conv1: x[16,256,256,3] -> h1b bf16[16,128,128,128]
__global__ __launch_bounds__(128) void k_conv1(const float* __restrict__ x, const float* __restrict__ w1,
                                               const float* __restrict__ b1, unsigned short* __restrict__ h1b) {
    __shared__ float smem[120]; // [iy 4][ix 10][c 3]
    int bx = blockIdx.x;
    int xg = bx & 31, y = (bx >> 5) & 127, b = bx >> 12;
    int x0 = xg << 2;
    int tid = threadIdx.x;
    if (tid < 120) {
        int c = tid % 3, sp = tid / 3;
        int iy = sp / 10, ix = sp - iy * 10;
        int gy = 2 * y - 1 + iy, gx = 2 * x0 - 1 + ix;
        float v = 0.f;
        if ((unsigned)gy < 256u && (unsigned)gx < 256u)
            v = x[((b * 256 + gy) * 256 + gx) * 3 + c];
        smem[tid] = v;
    }
    __syncthreads();
    int o = tid;
    float a0 = 0.f, a1 = 0.f, a2 = 0.f, a3 = 0.f;
    #pragma unroll
    for (int ky = 0; ky < 4; ++ky)
        #pragma unroll
        for (int kx = 0; kx < 4; ++kx)
            #pragma unroll
            for (int c = 0; c < 3; ++c) {
                float wv = w1[((ky * 4 + kx) * 3 + c) * 128 + o];
                a0 += smem[(ky * 10 + kx + 0) * 3 + c] * wv;
                a1 += smem[(ky * 10 + kx + 2) * 3 + c] * wv;
                a2 += smem[(ky * 10 + kx + 4) * 3 + c] * wv;
                a3 += smem[(ky * 10 + kx + 6) * 3 + c] * wv;
            }
    float bb = b1[o];
    int ob = ((b * 128 + y) * 128 + x0) * 128 + o;
    h1b[ob]       = f2b(leaky(a0 + bb));
    h1b[ob + 128] = f2b(leaky(a1 + bb));
    h1b[ob + 256] = f2b(leaky(a2 + bb));
    h1b[ob + 384] = f2b(leaky(a3 + bb));
}

// ---------------------------------------------------------------- conv2 MFMA + fused conv3: h1b -> enc fp32[16,64,64,64]
__global__ __launch_bounds__(256) void k_conv2(const unsigned short* __restrict__ h1b,
                                               const unsigned short* __restrict__ w2p,
                                               const float* __restrict__ b2,
                                               const unsigned short* __restrict__ w3p,
                                               const float* __restrict__ b3,
                                               float* __restrict__ enc) {
    __shared__ unsigned short h2s[64 * 256];   // [px][c] bf16, XOR-swizzled in 8-elem groups
    int bx = blockIdx.x;
    int y0 = bx & 63, b = bx >> 6;
    int tid = threadIdx.x;
    int wv = tid >> 6, lane = tid & 63;
    int lr = lane & 15, lk = lane >> 4;
    f32x4 acc[4][4];
    #pragma unroll
    for (int i = 0; i < 4; ++i)
        #pragma unroll
        for (int j = 0; j < 4; ++j) acc[i][j] = (f32x4){0.f, 0.f, 0.f, 0.f};

    const unsigned short* hbase = h1b + (size_t)b * (128 * 128 * 128);
    #pragma unroll 1
    for (int tap = 0; tap < 16; ++tap) {
        int ky = tap >> 2, kx = tap & 3;
        int gy = 2 * y0 + ky - 1;
        bool rowok = (unsigned)gy < 128u;
        const unsigned short* rowp = hbase + gy * (128 * 128);
        int gxl = 2 * lr + kx - 1;
        #pragma unroll
        for (int cc = 0; cc < 4; ++cc) {
            int c0 = cc * 32 + lk * 8;
            s16x8 aF[4];
            #pragma unroll
            for (int ms = 0; ms < 4; ++ms) {
                int gx = gxl + ms * 32;
                aF[ms] = ldz(rowp + gx * 128 + c0, rowok && (unsigned)gx < 128u);
            }
            const unsigned short* wp = w2p + (((tap * 4 + cc) * 16 + wv * 4) * 64 + lane) * 8;
            s16x8 bF[4];
            #pragma unroll
            for (int ns = 0; ns < 4; ++ns) bF[ns] = *(const s16x8*)(wp + ns * 512);
            #pragma unroll
            for (int ms = 0; ms < 4; ++ms)
                #pragma unroll
                for (int ns = 0; ns < 4; ++ns)
                    acc[ms][ns] = __builtin_amdgcn_mfma_f32_16x16x32_bf16(aF[ms], bF[ns], acc[ms][ns], 0, 0, 0);
        }
    }
    // epilogue 1: bias + leaky -> bf16 LDS tile (swizzled)
    int ocb = wv * 64;
    #pragma unroll
    for (int ns = 0; ns < 4; ++ns) {
        int c = ocb + ns * 16 + lr;
        float bb = b2[c];
        int cg = c >> 3, cj = c & 7;
        #pragma unroll
        for (int ms = 0; ms < 4; ++ms)
            #pragma unroll
            for (int r = 0; r < 4; ++r) {
                int px = ms * 16 + lk * 4 + r;
                h2s[px * 256 + ((cg ^ (px & 31)) << 3) + cj] = f2b(leaky(acc[ms][ns][r] + bb));
            }
    }
    __syncthreads();
    // conv3: 64px x 64d, K=256. Wave wv covers d = wv*16 + (0..15).
    f32x4 a3[4];
    #pragma unroll
    for (int i = 0; i < 4; ++i) a3[i] = (f32x4){0.f, 0.f, 0.f, 0.f};
    #pragma unroll
    for (int ks = 0; ks < 8; ++ks) {
        s16x8 bF = *(const s16x8*)(w3p + ((wv * 8 + ks) * 64 + lane) * 8);
        int cg = ks * 4 + lk;
        #pragma unroll
        for (int ms = 0; ms < 4; ++ms) {
            int px = lr + ms * 16;
            s16x8 aF = *(const s16x8*)(h2s + px * 256 + ((cg ^ (px & 31)) << 3));
            a3[ms] = __builtin_amdgcn_mfma_f32_16x16x32_bf16(aF, bF, a3[ms], 0, 0, 0);
        }
    }
    float bb3 = b3[wv * 16 + lr];
    float* outp = enc + ((size_t)(b * 64 + y0)) * 64 * 64;
    #pragma unroll
    for (int ms = 0; ms < 4; ++ms)
        #pragma unroll
        for (int r = 0; r < 4; ++r) {
            int px = ms * 16 + lk * 4 + r;
            outp[px * 64 + wv * 16 + lr] = a3[ms][r] + bb3;
        }
}

// ---------------------------------------------------------------- fused VQ via MFMA: dist+argmin+scatter+loss
// Block rb -> (b = rb>>6, w = rb&63): 64 rows (all c). Wave wv covers codes [wv*512, wv*512+512).
// Score S = enorm[k] - 2 f.e_k : C-init = enorm (col=lane&15=code), A = bf16(f), B = bf16(-2e) prepacked.
__global__ __launch_bounds__(256) void k_vq(const float* __restrict__ enc, const unsigned short* __restrict__ ebp,
                                            const float* __restrict__ emb, const float* __restrict__ enorm,
                                            unsigned short* __restrict__ qdec, float* __restrict__ loss) {
    __shared__ unsigned short f_sw[64 * 64];  // [row c][h], XOR-swizzled 8-elem groups (8 KB)
    __shared__ float en_sh[2048];             // 8 KB
    __shared__ float red_s[4 * 64];
    __shared__ int   red_k[4 * 64];
    __shared__ int   bk_sh[64];

    int rb = blockIdx.x;
    int b = rb >> 6, w = rb & 63;
    int tid = threadIdx.x;
    int cl = tid & 63, hg = tid >> 6;

    const float* encb = enc + b * 262144 + w * 64;
    // stage f as bf16 swizzled: f[c][h] = enc[b,h,w,c]
    #pragma unroll
    for (int hp = 0; hp < 16; ++hp) {
        int h = hp * 4 + hg;
        f_sw[cl * 64 + ((((h >> 3) ^ (cl & 7)) << 3) | (h & 7))] = f2b(encb[h * 4096 + cl]);
    }
    #pragma unroll
    for (int j = 0; j < 8; ++j) {
        int e = j * 256 + tid;
        en_sh[e] = enorm[e];
    }
    __syncthreads();

    int wv = tid >> 6, lane = tid & 63, lr = lane & 15, lk = lane >> 4;
    // A-fragments: rows ms*16+lr, k = ks*32 + lk*8 + j
    s16x8 aF[4][2];
    #pragma unroll
    for (int ms = 0; ms < 4; ++ms)
        #pragma unroll
        for (int ks = 0; ks < 2; ++ks) {
            int row = ms * 16 + lr;
            int grp = ((ks << 2) | lk) ^ (row & 7);
            aF[ms][ks] = *(const s16x8*)(f_sw + row * 64 + (grp << 3));
        }

    float bs[4][4]; int bkr[4][4];
    #pragma unroll
    for (int ms = 0; ms < 4; ++ms)
        #pragma unroll
        for (int r = 0; r < 4; ++r) { bs[ms][r] = 3.4e38f; bkr[ms][r] = 0; }

    const unsigned short* ebw = ebp + (size_t)(wv * 512) * 64;
    #pragma unroll 1
    for (int j = 0; j < 32; ++j) {
        const unsigned short* ep = ebw + (j * 16 + lr) * 64 + lk * 8;
        s16x8 bF0 = *(const s16x8*)(ep);
        s16x8 bF1 = *(const s16x8*)(ep + 32);
        int kg = wv * 512 + j * 16 + lr;
        float en = en_sh[kg];
        #pragma unroll
        for (int ms = 0; ms < 4; ++ms) {
            f32x4 d = {en, en, en, en};
            d = __builtin_amdgcn_mfma_f32_16x16x32_bf16(aF[ms][0], bF0, d, 0, 0, 0);
            d = __builtin_amdgcn_mfma_f32_16x16x32_bf16(aF[ms][1], bF1, d, 0, 0, 0);
            #pragma unroll
            for (int r = 0; r < 4; ++r) {
                if (d[r] < bs[ms][r]) { bs[ms][r] = d[r]; bkr[ms][r] = kg; }
            }
        }
    }

    // butterfly over the 16 code-residues (lanes with same lk)
    #pragma unroll
    for (int off = 1; off <= 8; off <<= 1) {
        #pragma unroll
        for (int ms = 0; ms < 4; ++ms)
            #pragma unroll
            for (int r = 0; r < 4; ++r) {
                float os = __shfl_xor(bs[ms][r], off, 64);
                int ok = __shfl_xor(bkr[ms][r], off, 64);
                if (os < bs[ms][r] || (os == bs[ms][r] && ok < bkr[ms][r])) {
                    bs[ms][r] = os; bkr[ms][r] = ok;
                }
            }
    }
    if (lr == 0) {
        #pragma unroll
        for (int ms = 0; ms < 4; ++ms)
            #pragma unroll
            for (int r = 0; r < 4; ++r) {
                int row = ms * 16 + lk * 4 + r;
                red_s[wv * 64 + row] = bs[ms][r];
                red_k[wv * 64 + row] = bkr[ms][r];
            }
    }
    __syncthreads();
    if (tid < 64) {
        float s0 = red_s[tid]; int k0 = red_k[tid];
        #pragma unroll
        for (int v = 1; v < 4; ++v) {   // ascending wave = ascending code range -> first-min
            float s = red_s[v * 64 + tid]; int k = red_k[v * 64 + tid];
            if (s < s0 || (s == s0 && k < k0)) { s0 = s; k0 = k; }
        }
        bk_sh[tid] = k0;
    }
    __syncthreads();

    // epilogue: loss (fp32 enc) + quant scatter
    int bcode = bk_sh[cl];
    const float* ev = emb + bcode * 64;
    unsigned short* qd = qdec + b * 262144 + w * 64 + cl;
    float ls = 0.f;
    #pragma unroll
    for (int hp = 0; hp < 16; ++hp) {
        int h = hp * 4 + hg;
        float e = ev[h];
        float f = encb[h * 4096 + cl];
        float d = e - f;
        ls += d * d;
        qd[h * 4096] = f2b(e);
    }
    #pragma unroll
    for (int off = 32; off; off >>= 1) ls += __shfl_xor(ls, off, 64);
    if ((tid & 63) == 0) atomicAdd(loss, ls);
}

// ---------------------------------------------------------------- deconv1 MFMA: qdec bf16 -> g bf16[16,128,128,256]
__global__ __launch_bounds__(256) void k_deconv1(const unsigned short* __restrict__ qdec,
                                                 const unsigned short* __restrict__ dw1p,
                                                 const float* __restrict__ db1, unsigned short* __restrict__ g) {
    int bx = blockIdx.x;
    int parx = bx & 1, y = (bx >> 1) & 127, b = bx >> 8;
    int pary = y & 1;
    int h0 = (y - 2 + pary) >> 1;
    int tid = threadIdx.x;
    int wv = tid >> 6, lane = tid & 63;
    int lr = lane & 15, lk = lane >> 4;
    f32x4 acc[4][4];
    #pragma unroll
    for (int i = 0; i < 4; ++i)
        #pragma unroll
        for (int j = 0; j < 4; ++j) acc[i][j] = (f32x4){0.f, 0.f, 0.f, 0.f};

    const unsigned short* qb = qdec + (size_t)b * (64 * 64 * 64);
    #pragma unroll
    for (int tky = 0; tky < 2; ++tky) {
        int h = h0 + tky;
        bool hok = (unsigned)h < 64u;
        const unsigned short* rowp = qb + h * (64 * 64);
        #pragma unroll
        for (int tkx = 0; tkx < 2; ++tkx) {
            int tap = (pary + 2 * tky) * 4 + parx + 2 * tkx;
            int wbase = lr + parx + tkx - 1;
            #pragma unroll
            for (int cc = 0; cc < 2; ++cc) {
                int c0 = cc * 32 + lk * 8;
                s16x8 aF[4];
                #pragma unroll
                for (int ms = 0; ms < 4; ++ms) {
                    int w = wbase + ms * 16;
                    aF[ms] = ldz(rowp + w * 64 + c0, hok && (unsigned)w < 64u);
                }
                const unsigned short* wp = dw1p + (((tap * 2 + cc) * 16 + wv * 4) * 64 + lane) * 8;
                s16x8 bF[4];
                #pragma unroll
                for (int ns = 0; ns < 4; ++ns) bF[ns] = *(const s16x8*)(wp + ns * 512);
                #pragma unroll
                for (int ms = 0; ms < 4; ++ms)
                    #pragma unroll
                    for (int ns = 0; ns < 4; ++ns)
                        acc[ms][ns] = __builtin_amdgcn_mfma_f32_16x16x32_bf16(aF[ms], bF[ns], acc[ms][ns], 0, 0, 0);
            }
        }
    }
    int ocb = wv * 64;
    unsigned short* gp = g + ((size_t)(b * 128 + y)) * 128 * 256;
    #pragma unroll
    for (int ns = 0; ns < 4; ++ns) {
        float bb = db1[ocb + ns * 16 + lr];
        #pragma unroll
        for (int ms = 0; ms < 4; ++ms)
            #pragma unroll
            for (int r = 0; r < 4; ++r) {
                int u = ms * 16 + lk * 4 + r;
                int xo = 2 * u + parx;
                gp[xo * 256 + ocb + ns * 16 + lr] = f2b(leaky(acc[ms][ns][r] + bb));
            }
    }
}

// ---------------------------------------------------------------- deconv2 MFMA: g bf16 -> recon fp32[16,256,256,3], tanh
__global__ __launch_bounds__(256) void k_deconv2(const unsigned short* __restrict__ g,
                                                 const unsigned short* __restrict__ dwp,
                                                 const float* __restrict__ db2, float* __restrict__ out,
                                                 const float* __restrict__ loss) {
    int bx = blockIdx.x;
    int swz = (bx & 7) * 512 + (bx >> 3);     // XCD-chunked
    int b = swz >> 8, y = swz & 255;
    int tid = threadIdx.x;
    int wv = tid >> 6, lane = tid & 63;
    int lr = lane & 15, lk = lane >> 4;
    int px0 = wv >> 1, half = wv & 1;
    int py = y & 1;
    int h0 = (y - 2 + py) >> 1;

    f32x4 acc[4];
    #pragma unroll
    for (int i = 0; i < 4; ++i) acc[i] = (f32x4){0.f, 0.f, 0.f, 0.f};

    const unsigned short* dwb = dwp + (size_t)(py * 2 + px0) * 32 * 512;
    const unsigned short* gb = g + (size_t)b * (128 * 128 * 256);

    #pragma unroll
    for (int tap = 0; tap < 4; ++tap) {
        int tky = tap >> 1, tkx = tap & 1;
        int h = h0 + tky;
        bool hok = (unsigned)h < 128u;
        const unsigned short* rowp = gb + h * (128 * 256);
        int wofs = px0 - 1 + tkx;
        #pragma unroll
        for (int k8 = 0; k8 < 8; ++k8) {
            int ks = tap * 8 + k8;
            int c0 = k8 * 32 + lk * 8;
            s16x8 bF = *(const s16x8*)(dwb + (ks * 64 + lane) * 8);
            #pragma unroll
            for (int ms = 0; ms < 4; ++ms) {
                int n = half * 64 + ms * 16 + lr;
                int w = n + wofs;
                s16x8 aF = ldz(rowp + w * 256 + c0, hok && (unsigned)w < 128u);
                acc[ms] = __builtin_amdgcn_mfma_f32_16x16x32_bf16(aF, bF, acc[ms], 0, 0, 0);
            }
        }
    }
    if (lr < 3) {
        float bb = db2[lr];
        #pragma unroll
        for (int ms = 0; ms < 4; ++ms)
            #pragma unroll
            for (int r = 0; r < 4; ++r) {
                int n = half * 64 + ms * 16 + lk * 4 + r;
                int x = 2 * n + px0;
                out[((size_t)b * 65536 + y * 256 + x) * 3 + lr] = tanhf(acc[ms][r] + bb);
            }
    }
    if (bx == 0 && tid == 0)
        out[3145728] = loss[0] * (1.25f / 4194304.f);
}

// ---------------------------------------------------------------- launch
extern "C" void kernel_launch(void* const* d_in, const int* in_sizes, int n_in,
                              void* d_out, int out_size, void* d_ws, size_t ws_size,
                              hipStream_t stream) {
    const float* x   = (const float*)d_in[0];
    const float* emb = (const float*)d_in[1];
    const float* w1  = (const float*)d_in[2];
    const float* b1  = (const float*)d_in[3];
    const float* w2  = (const float*)d_in[4];
    const float* b2  = (const float*)d_in[5];
    const float* w3  = (const float*)d_in[6];
    const float* b3  = (const float*)d_in[7];
    const float* dw1 = (const float*)d_in[8];
    const float* db1 = (const float*)d_in[9];
    const float* dw2 = (const float*)d_in[10];
    const float* db2 = (const float*)d_in[11];
    float* out = (float*)d_out;
    float* ws  = (float*)d_ws;

    if (ws_size < (size_t)40347664 * 4) return;

    unsigned short* h1b  = (unsigned short*)ws;            // bf16, later overlapped by g
    unsigned short* g    = (unsigned short*)ws;            // bf16 [16,128,128,256]
    float* enc   = ws + 33554432;
    unsigned short* qdec = (unsigned short*)(ws + 37748736);
    float* enorm = ws + 39845888;
    float* loss  = ws + 39847936;
    unsigned short* w2p  = (unsigned short*)(ws + 39847952);
    unsigned short* dw1p = (unsigned short*)(ws + 40110096);
    unsigned short* w3p  = (unsigned short*)(ws + 40241168);
    unsigned short* dwp  = (unsigned short*)(ws + 40249360);
    unsigned short* ebp  = (unsigned short*)(ws + 40282128);

    k_prep   <<<8,     256, 0, stream>>>(emb, enorm, loss, ebp);
    k_pack   <<<3392,  256, 0, stream>>>(w2, dw1, w3, dw2, w2p, dw1p, w3p, dwp);
    k_conv1  <<<65536, 128, 0, stream>>>(x, w1, b1, h1b);
    k_conv2  <<<1024,  256, 0, stream>>>(h1b, w2p, b2, w3p, b3, enc);
    k_vq     <<<1024,  256, 0, stream>>>(enc, ebp, emb, enorm, qdec, loss);
    k_deconv1<<<4096,  256, 0, stream>>>(qdec, dw1p, db1, g);
    k_deconv2<<<4096,  256, 0, stream>>>(g, dwp, db2, out, loss);
}

// Round 7
// 581.490 us; speedup vs baseline: 7.1884x; 1.3166x over previous
//
#include <hip/hip_runtime.h>
#include <math.h>

// VQ-VAE forward. MI355X / gfx950. bf16-MFMA conv2(+fused conv3), vq, deconv1, deconv2(LDS-staged).
// prep -> pack -> conv1(bf16 out) -> conv2+3(MFMA, enc out) -> vq(MFMA) -> deconv1(MFMA) -> deconv2(MFMA+LDS)
// Workspace (float slots):
//   [0)          h1b bf16 (16,777,216 slots); later g bf16 (33,554,432 slots)
//   [33554432)   enc fp32  4,194,304
//   [37748736)   qdec bf16 (2,097,152 slots)
//   [39845888)   enorm     2,048
//   [39847936)   loss      16
//   [39847952)   w2p  bf16 (262,144 slots)
//   [40110096)   dw1p bf16 (131,072 slots)
//   [40241168)   w3p  bf16 (8,192 slots)
//   [40249360)   dwp  bf16 (32,768 slots)
//   [40282128)   ebp  bf16 (65,536 slots) = bf16(-2*emb)
//   total 40,347,664 floats = 161.4 MB

typedef short s16x8 __attribute__((ext_vector_type(8)));
typedef float f32x4 __attribute__((ext_vector_type(4)));

#define LD4(p) (*(const float4*)(p))

__device__ __forceinline__ float leaky(float v) { return v >= 0.f ? v : 0.01f * v; }
__device__ __forceinline__ unsigned short f2b(float f) {
    union { float f; unsigned u; } v; v.f = f;
    unsigned r = v.u + 0x7fffu + ((v.u >> 16) & 1u);
    return (unsigned short)(r >> 16);
}
__device__ __forceinline__ s16x8 ldz(const unsigned short* p, bool ok) {
    s16x8 z = {0,0,0,0,0,0,0,0};
    return ok ? *(const s16x8*)p : z;
}

// ---------------------------------------------------------------- prep: enorm + ebp(-2e bf16) + loss init
__global__ __launch_bounds__(256) void k_prep(const float* __restrict__ emb,
                                              float* __restrict__ enorm, float* __restrict__ loss,
                                              unsigned short* __restrict__ ebp) {
    int t = blockIdx.x * 256 + threadIdx.x;
    if (t == 0) loss[0] = 0.f;
    if (t < 2048) {
        const float* e = emb + t * 64;
        float s = 0.f;
        #pragma unroll
        for (int h = 0; h < 64; ++h) {
            float ev = e[h];
            s += ev * ev;
            ebp[t * 64 + h] = f2b(-2.f * ev);
        }
        enorm[t] = s;
    }
}

// ---------------------------------------------------------------- pack bf16 MFMA fragments
__global__ __launch_bounds__(256) void k_pack(const float* __restrict__ w2, const float* __restrict__ dw1,
                                              const float* __restrict__ w3, const float* __restrict__ dw2,
                                              unsigned short* __restrict__ w2p, unsigned short* __restrict__ dw1p,
                                              unsigned short* __restrict__ w3p, unsigned short* __restrict__ dwp) {
    int t = blockIdx.x * 256 + threadIdx.x;
    if (t < 524288) {
        int j = t & 7, lane = (t >> 3) & 63, nsg = (t >> 9) & 15, cc = (t >> 13) & 3, tap = t >> 15;
        int c = cc * 32 + ((lane >> 4) << 3) + j;
        int oc = nsg * 16 + (lane & 15);
        w2p[t] = f2b(w2[(tap * 128 + c) * 256 + oc]);
    } else if (t < 786432) {
        int u = t - 524288;
        int j = u & 7, lane = (u >> 3) & 63, nsg = (u >> 9) & 15, cc = (u >> 13) & 1, tap = u >> 14;
        int c = cc * 32 + ((lane >> 4) << 3) + j;
        int oc = nsg * 16 + (lane & 15);
        dw1p[u] = f2b(dw1[(tap * 64 + c) * 256 + oc]);
    } else if (t < 802816) {
        int v = t - 786432;
        int j = v & 7, lane = (v >> 3) & 63, ks = (v >> 9) & 7, wv = v >> 12;
        int c = ks * 32 + ((lane >> 4) << 3) + j;
        int d = wv * 16 + (lane & 15);
        w3p[v] = f2b(w3[c * 64 + d]);
    } else {
        int u2 = t - 802816;  // 65536
        int j = u2 & 7, lane = (u2 >> 3) & 63, ks = (u2 >> 9) & 31, par = u2 >> 14;
        int py = par >> 1, px0 = par & 1;
        int k = ks * 32 + ((lane >> 4) << 3) + j;
        int tap = k >> 8, c = k & 255;
        int ky = py + 2 * (tap >> 1), kx = px0 + 2 * (tap & 1);
        int oc = lane & 15;
        dwp[u2] = (oc < 3) ? f2b(dw2[((ky * 4 + kx) * 256 + c) * 3 + oc]) : (unsigned short)0;
    }
}

// ---------------------------------------------------------------- conv1: x[16,256,256,3] -> h1b bf16[16,128,128,128]
__global__ __launch_bounds__(128) void k_conv1(const float* __restrict__ x, const float* __restrict__ w1,
                                               const float* __restrict__ b1, unsigned short* __restrict__ h1b) {
    __shared__ float smem[120]; // [iy 4][ix 10][c 3]
    int bx = blockIdx.x;
    int xg = bx & 31, y = (bx >> 5) & 127, b = bx >> 12;
    int x0 = xg << 2;
    int tid = threadIdx.x;
    if (tid < 120) {
        int c = tid % 3, sp = tid / 3;
        int iy = sp / 10, ix = sp - iy * 10;
        int gy = 2 * y - 1 + iy, gx = 2 * x0 - 1 + ix;
        float v = 0.f;
        if ((unsigned)gy < 256u && (unsigned)gx < 256u)
            v = x[((b * 256 + gy) * 256 + gx) * 3 + c];
        smem[tid] = v;
    }
    __syncthreads();
    int o = tid;
    float a0 = 0.f, a1 = 0.f, a2 = 0.f, a3 = 0.f;
    #pragma unroll
    for (int ky = 0; ky < 4; ++ky)
        #pragma unroll
        for (int kx = 0; kx < 4; ++kx)
            #pragma unroll
            for (int c = 0; c < 3; ++c) {
                float wv = w1[((ky * 4 + kx) * 3 + c) * 128 + o];
                a0 += smem[(ky * 10 + kx + 0) * 3 + c] * wv;
                a1 += smem[(ky * 10 + kx + 2) * 3 + c] * wv;
                a2 += smem[(ky * 10 + kx + 4) * 3 + c] * wv;
                a3 += smem[(ky * 10 + kx + 6) * 3 + c] * wv;
            }
    float bb = b1[o];
    int ob = ((b * 128 + y) * 128 + x0) * 128 + o;
    h1b[ob]       = f2b(leaky(a0 + bb));
    h1b[ob + 128] = f2b(leaky(a1 + bb));
    h1b[ob + 256] = f2b(leaky(a2 + bb));
    h1b[ob + 384] = f2b(leaky(a3 + bb));
}

// ---------------------------------------------------------------- conv2 MFMA + fused conv3: h1b -> enc fp32[16,64,64,64]
__global__ __launch_bounds__(256) void k_conv2(const unsigned short* __restrict__ h1b,
                                               const unsigned short* __restrict__ w2p,
                                               const float* __restrict__ b2,
                                               const unsigned short* __restrict__ w3p,
                                               const float* __restrict__ b3,
                                               float* __restrict__ enc) {
    __shared__ unsigned short h2s[64 * 256];   // [px][c] bf16, XOR-swizzled in 8-elem groups
    int bx = blockIdx.x;
    int y0 = bx & 63, b = bx >> 6;
    int tid = threadIdx.x;
    int wv = tid >> 6, lane = tid & 63;
    int lr = lane & 15, lk = lane >> 4;
    f32x4 acc[4][4];
    #pragma unroll
    for (int i = 0; i < 4; ++i)
        #pragma unroll
        for (int j = 0; j < 4; ++j) acc[i][j] = (f32x4){0.f, 0.f, 0.f, 0.f};

    const unsigned short* hbase = h1b + (size_t)b * (128 * 128 * 128);
    #pragma unroll 1
    for (int tap = 0; tap < 16; ++tap) {
        int ky = tap >> 2, kx = tap & 3;
        int gy = 2 * y0 + ky - 1;
        bool rowok = (unsigned)gy < 128u;
        const unsigned short* rowp = hbase + gy * (128 * 128);
        int gxl = 2 * lr + kx - 1;
        #pragma unroll
        for (int cc = 0; cc < 4; ++cc) {
            int c0 = cc * 32 + lk * 8;
            s16x8 aF[4];
            #pragma unroll
            for (int ms = 0; ms < 4; ++ms) {
                int gx = gxl + ms * 32;
                aF[ms] = ldz(rowp + gx * 128 + c0, rowok && (unsigned)gx < 128u);
            }
            const unsigned short* wp = w2p + (((tap * 4 + cc) * 16 + wv * 4) * 64 + lane) * 8;
            s16x8 bF[4];
            #pragma unroll
            for (int ns = 0; ns < 4; ++ns) bF[ns] = *(const s16x8*)(wp + ns * 512);
            #pragma unroll
            for (int ms = 0; ms < 4; ++ms)
                #pragma unroll
                for (int ns = 0; ns < 4; ++ns)
                    acc[ms][ns] = __builtin_amdgcn_mfma_f32_16x16x32_bf16(aF[ms], bF[ns], acc[ms][ns], 0, 0, 0);
        }
    }
    // epilogue 1: bias + leaky -> bf16 LDS tile (swizzled)
    int ocb = wv * 64;
    #pragma unroll
    for (int ns = 0; ns < 4; ++ns) {
        int c = ocb + ns * 16 + lr;
        float bb = b2[c];
        int cg = c >> 3, cj = c & 7;
        #pragma unroll
        for (int ms = 0; ms < 4; ++ms)
            #pragma unroll
            for (int r = 0; r < 4; ++r) {
                int px = ms * 16 + lk * 4 + r;
                h2s[px * 256 + ((cg ^ (px & 31)) << 3) + cj] = f2b(leaky(acc[ms][ns][r] + bb));
            }
    }
    __syncthreads();
    // conv3: 64px x 64d, K=256. Wave wv covers d = wv*16 + (0..15).
    f32x4 a3[4];
    #pragma unroll
    for (int i = 0; i < 4; ++i) a3[i] = (f32x4){0.f, 0.f, 0.f, 0.f};
    #pragma unroll
    for (int ks = 0; ks < 8; ++ks) {
        s16x8 bF = *(const s16x8*)(w3p + ((wv * 8 + ks) * 64 + lane) * 8);
        int cg = ks * 4 + lk;
        #pragma unroll
        for (int ms = 0; ms < 4; ++ms) {
            int px = lr + ms * 16;
            s16x8 aF = *(const s16x8*)(h2s + px * 256 + ((cg ^ (px & 31)) << 3));
            a3[ms] = __builtin_amdgcn_mfma_f32_16x16x32_bf16(aF, bF, a3[ms], 0, 0, 0);
        }
    }
    float bb3 = b3[wv * 16 + lr];
    float* outp = enc + ((size_t)(b * 64 + y0)) * 64 * 64;
    #pragma unroll
    for (int ms = 0; ms < 4; ++ms)
        #pragma unroll
        for (int r = 0; r < 4; ++r) {
            int px = ms * 16 + lk * 4 + r;
            outp[px * 64 + wv * 16 + lr] = a3[ms][r] + bb3;
        }
}

// ---------------------------------------------------------------- fused VQ via MFMA: dist+argmin+scatter+loss
__global__ __launch_bounds__(256) void k_vq(const float* __restrict__ enc, const unsigned short* __restrict__ ebp,
                                            const float* __restrict__ emb, const float* __restrict__ enorm,
                                            unsigned short* __restrict__ qdec, float* __restrict__ loss) {
    __shared__ unsigned short f_sw[64 * 64];  // [row c][h], XOR-swizzled 8-elem groups (8 KB)
    __shared__ float en_sh[2048];             // 8 KB
    __shared__ float red_s[4 * 64];
    __shared__ int   red_k[4 * 64];
    __shared__ int   bk_sh[64];

    int rb = blockIdx.x;
    int b = rb >> 6, w = rb & 63;
    int tid = threadIdx.x;
    int cl = tid & 63, hg = tid >> 6;

    const float* encb = enc + b * 262144 + w * 64;
    #pragma unroll
    for (int hp = 0; hp < 16; ++hp) {
        int h = hp * 4 + hg;
        f_sw[cl * 64 + ((((h >> 3) ^ (cl & 7)) << 3) | (h & 7))] = f2b(encb[h * 4096 + cl]);
    }
    #pragma unroll
    for (int j = 0; j < 8; ++j) {
        int e = j * 256 + tid;
        en_sh[e] = enorm[e];
    }
    __syncthreads();

    int wv = tid >> 6, lane = tid & 63, lr = lane & 15, lk = lane >> 4;
    s16x8 aF[4][2];
    #pragma unroll
    for (int ms = 0; ms < 4; ++ms)
        #pragma unroll
        for (int ks = 0; ks < 2; ++ks) {
            int row = ms * 16 + lr;
            int grp = ((ks << 2) | lk) ^ (row & 7);
            aF[ms][ks] = *(const s16x8*)(f_sw + row * 64 + (grp << 3));
        }

    float bs[4][4]; int bkr[4][4];
    #pragma unroll
    for (int ms = 0; ms < 4; ++ms)
        #pragma unroll
        for (int r = 0; r < 4; ++r) { bs[ms][r] = 3.4e38f; bkr[ms][r] = 0; }

    const unsigned short* ebw = ebp + (size_t)(wv * 512) * 64;
    #pragma unroll 1
    for (int j = 0; j < 32; ++j) {
        const unsigned short* ep = ebw + (j * 16 + lr) * 64 + lk * 8;
        s16x8 bF0 = *(const s16x8*)(ep);
        s16x8 bF1 = *(const s16x8*)(ep + 32);
        int kg = wv * 512 + j * 16 + lr;
        float en = en_sh[kg];
        #pragma unroll
        for (int ms = 0; ms < 4; ++ms) {
            f32x4 d = {en, en, en, en};
            d = __builtin_amdgcn_mfma_f32_16x16x32_bf16(aF[ms][0], bF0, d, 0, 0, 0);
            d = __builtin_amdgcn_mfma_f32_16x16x32_bf16(aF[ms][1], bF1, d, 0, 0, 0);
            #pragma unroll
            for (int r = 0; r < 4; ++r) {
                if (d[r] < bs[ms][r]) { bs[ms][r] = d[r]; bkr[ms][r] = kg; }
            }
        }
    }

    #pragma unroll
    for (int off = 1; off <= 8; off <<= 1) {
        #pragma unroll
        for (int ms = 0; ms < 4; ++ms)
            #pragma unroll
            for (int r = 0; r < 4; ++r) {
                float os = __shfl_xor(bs[ms][r], off, 64);
                int ok = __shfl_xor(bkr[ms][r], off, 64);
                if (os < bs[ms][r] || (os == bs[ms][r] && ok < bkr[ms][r])) {
                    bs[ms][r] = os; bkr[ms][r] = ok;
                }
            }
    }
    if (lr == 0) {
        #pragma unroll
        for (int ms = 0; ms < 4; ++ms)
            #pragma unroll
            for (int r = 0; r < 4; ++r) {
                int row = ms * 16 + lk * 4 + r;
                red_s[wv * 64 + row] = bs[ms][r];
                red_k[wv * 64 + row] = bkr[ms][r];
            }
    }
    __syncthreads();
    if (tid < 64) {
        float s0 = red_s[tid]; int k0 = red_k[tid];
        #pragma unroll
        for (int v = 1; v < 4; ++v) {
            float s = red_s[v * 64 + tid]; int k = red_k[v * 64 + tid];
            if (s < s0 || (s == s0 && k < k0)) { s0 = s; k0 = k; }
        }
        bk_sh[tid] = k0;
    }
    __syncthreads();

    int bcode = bk_sh[cl];
    const float* ev = emb + bcode * 64;
    unsigned short* qd = qdec + b * 262144 + w * 64 + cl;
    float ls = 0.f;
    #pragma unroll
    for (int hp = 0; hp < 16; ++hp) {
        int h = hp * 4 + hg;
        float e = ev[h];
        float f = encb[h * 4096 + cl];
        float d = e - f;
        ls += d * d;
        qd[h * 4096] = f2b(e);
    }
    #pragma unroll
    for (int off = 32; off; off >>= 1) ls += __shfl_xor(ls, off, 64);
    if ((tid & 63) == 0) atomicAdd(loss, ls);
}

// ---------------------------------------------------------------- deconv1 MFMA: qdec bf16 -> g bf16[16,128,128,256]
__global__ __launch_bounds__(256) void k_deconv1(const unsigned short* __restrict__ qdec,
                                                 const unsigned short* __restrict__ dw1p,
                                                 const float* __restrict__ db1, unsigned short* __restrict__ g) {
    int bx = blockIdx.x;
    int parx = bx & 1, y = (bx >> 1) & 127, b = bx >> 8;
    int pary = y & 1;
    int h0 = (y - 2 + pary) >> 1;
    int tid = threadIdx.x;
    int wv = tid >> 6, lane = tid & 63;
    int lr = lane & 15, lk = lane >> 4;
    f32x4 acc[4][4];
    #pragma unroll
    for (int i = 0; i < 4; ++i)
        #pragma unroll
        for (int j = 0; j < 4; ++j) acc[i][j] = (f32x4){0.f, 0.f, 0.f, 0.f};

    const unsigned short* qb = qdec + (size_t)b * (64 * 64 * 64);
    #pragma unroll
    for (int tky = 0; tky < 2; ++tky) {
        int h = h0 + tky;
        bool hok = (unsigned)h < 64u;
        const unsigned short* rowp = qb + h * (64 * 64);
        #pragma unroll
        for (int tkx = 0; tkx < 2; ++tkx) {
            int tap = (pary + 2 * tky) * 4 + parx + 2 * tkx;
            int wbase = lr + parx + tkx - 1;
            #pragma unroll
            for (int cc = 0; cc < 2; ++cc) {
                int c0 = cc * 32 + lk * 8;
                s16x8 aF[4];
                #pragma unroll
                for (int ms = 0; ms < 4; ++ms) {
                    int w = wbase + ms * 16;
                    aF[ms] = ldz(rowp + w * 64 + c0, hok && (unsigned)w < 64u);
                }
                const unsigned short* wp = dw1p + (((tap * 2 + cc) * 16 + wv * 4) * 64 + lane) * 8;
                s16x8 bF[4];
                #pragma unroll
                for (int ns = 0; ns < 4; ++ns) bF[ns] = *(const s16x8*)(wp + ns * 512);
                #pragma unroll
                for (int ms = 0; ms < 4; ++ms)
                    #pragma unroll
                    for (int ns = 0; ns < 4; ++ns)
                        acc[ms][ns] = __builtin_amdgcn_mfma_f32_16x16x32_bf16(aF[ms], bF[ns], acc[ms][ns], 0, 0, 0);
            }
        }
    }
    int ocb = wv * 64;
    unsigned short* gp = g + ((size_t)(b * 128 + y)) * 128 * 256;
    #pragma unroll
    for (int ns = 0; ns < 4; ++ns) {
        float bb = db1[ocb + ns * 16 + lr];
        #pragma unroll
        for (int ms = 0; ms < 4; ++ms)
            #pragma unroll
            for (int r = 0; r < 4; ++r) {
                int u = ms * 16 + lk * 4 + r;
                int xo = 2 * u + parx;
                gp[xo * 256 + ocb + ns * 16 + lr] = f2b(leaky(acc[ms][ns][r] + bb));
            }
    }
}

// ---------------------------------------------------------------- deconv2 MFMA, LDS-staged: g bf16 -> recon fp32, tanh
// Block = (b, m): computes output rows y = 2m-1 and 2m (both consume g rows m-1, m).
// 4 waves = 2 y-values x 2 x-parities; each M=128 n, N=16(3 used), K=1024.
// LDS: [tky 2][w 128][chalf 128] bf16 = 64 KB per cc half; cg ^= (w&15) swizzle.
__global__ __launch_bounds__(256) void k_deconv2(const unsigned short* __restrict__ g,
                                                 const unsigned short* __restrict__ dwp,
                                                 const float* __restrict__ db2, float* __restrict__ out,
                                                 const float* __restrict__ loss) {
    __shared__ unsigned short gs[2][128][128];
    int bx = blockIdx.x;
    int swz = (bx % 8) * 258 + bx / 8;        // 2064 blocks; XCD-chunked
    int b = swz / 129, m = swz % 129;
    int tid = threadIdx.x;
    int wv = tid >> 6, lane = tid & 63;
    int lr = lane & 15, lk = lane >> 4;
    int yi = wv >> 1, px0 = wv & 1;
    int y = 2 * m - 1 + yi;
    int py = yi ^ 1;

    f32x4 acc[8];
    #pragma unroll
    for (int i = 0; i < 8; ++i) acc[i] = (f32x4){0.f, 0.f, 0.f, 0.f};

    const unsigned short* gb = g + (size_t)b * (128 * 128 * 256);
    const unsigned short* dwb = dwp + (size_t)(py * 2 + px0) * 32 * 512;

    #pragma unroll 1
    for (int cc = 0; cc < 2; ++cc) {
        __syncthreads();
        // stage rows h = m-1+tky, channel half cc (coalesced 256B chunks, full lines)
        #pragma unroll
        for (int i = 0; i < 16; ++i) {
            int ch = i * 256 + tid;             // 0..4095
            int cg = ch & 15;
            int w  = (ch >> 4) & 127;
            int tky = ch >> 11;
            int h = m - 1 + tky;
            s16x8 v = {0,0,0,0,0,0,0,0};
            if ((unsigned)h < 128u)
                v = *(const s16x8*)(gb + h * (128 * 256) + w * 256 + cc * 128 + cg * 8);
            *(s16x8*)(&gs[tky][w][(cg ^ (w & 15)) << 3]) = v;
        }
        __syncthreads();
        #pragma unroll
        for (int tky = 0; tky < 2; ++tky) {
            #pragma unroll
            for (int tkx = 0; tkx < 2; ++tkx) {
                int tap = tky * 2 + tkx;
                int wofs = px0 - 1 + tkx;
                #pragma unroll
                for (int k8 = 0; k8 < 4; ++k8) {
                    int ks = tap * 8 + cc * 4 + k8;
                    s16x8 bF = *(const s16x8*)(dwb + (ks * 64 + lane) * 8);
                    int cg = k8 * 4 + lk;
                    #pragma unroll
                    for (int ms = 0; ms < 8; ++ms) {
                        int w = ms * 16 + lr + wofs;
                        s16x8 aF = {0,0,0,0,0,0,0,0};
                        if ((unsigned)w < 128u)
                            aF = *(const s16x8*)(&gs[tky][w][(cg ^ (w & 15)) << 3]);
                        acc[ms] = __builtin_amdgcn_mfma_f32_16x16x32_bf16(aF, bF, acc[ms], 0, 0, 0);
                    }
                }
            }
        }
    }
    if ((unsigned)y < 256u && lr < 3) {
        float bb = db2[lr];
        #pragma unroll
        for (int ms = 0; ms < 8; ++ms)
            #pragma unroll
            for (int r = 0; r < 4; ++r) {
                int n = ms * 16 + lk * 4 + r;
                int x = 2 * n + px0;
                out[((size_t)b * 65536 + y * 256 + x) * 3 + lr] = tanhf(acc[ms][r] + bb);
            }
    }
    if (bx == 0 && tid == 0)
        out[3145728] = loss[0] * (1.25f / 4194304.f);
}

// ---------------------------------------------------------------- launch
extern "C" void kernel_launch(void* const* d_in, const int* in_sizes, int n_in,
                              void* d_out, int out_size, void* d_ws, size_t ws_size,
                              hipStream_t stream) {
    const float* x   = (const float*)d_in[0];
    const float* emb = (const float*)d_in[1];
    const float* w1  = (const float*)d_in[2];
    const float* b1  = (const float*)d_in[3];
    const float* w2  = (const float*)d_in[4];
    const float* b2  = (const float*)d_in[5];
    const float* w3  = (const float*)d_in[6];
    const float* b3  = (const float*)d_in[7];
    const float* dw1 = (const float*)d_in[8];
    const float* db1 = (const float*)d_in[9];
    const float* dw2 = (const float*)d_in[10];
    const float* db2 = (const float*)d_in[11];
    float* out = (float*)d_out;
    float* ws  = (float*)d_ws;

    if (ws_size < (size_t)40347664 * 4) return;

    unsigned short* h1b  = (unsigned short*)ws;            // bf16, later overlapped by g
    unsigned short* g    = (unsigned short*)ws;            // bf16 [16,128,128,256]
    float* enc   = ws + 33554432;
    unsigned short* qdec = (unsigned short*)(ws + 37748736);
    float* enorm = ws + 39845888;
    float* loss  = ws + 39847936;
    unsigned short* w2p  = (unsigned short*)(ws + 39847952);
    unsigned short* dw1p = (unsigned short*)(ws + 40110096);
    unsigned short* w3p  = (unsigned short*)(ws + 40241168);
    unsigned short* dwp  = (unsigned short*)(ws + 40249360);
    unsigned short* ebp  = (unsigned short*)(ws + 40282128);

    k_prep   <<<8,     256, 0, stream>>>(emb, enorm, loss, ebp);
    k_pack   <<<3392,  256, 0, stream>>>(w2, dw1, w3, dw2, w2p, dw1p, w3p, dwp);
    k_conv1  <<<65536, 128, 0, stream>>>(x, w1, b1, h1b);
    k_conv2  <<<1024,  256, 0, stream>>>(h1b, w2p, b2, w3p, b3, enc);
    k_vq     <<<1024,  256, 0, stream>>>(enc, ebp, emb, enorm, qdec, loss);
    k_deconv1<<<4096,  256, 0, stream>>>(qdec, dw1p, db1, g);
    k_deconv2<<<2064,  256, 0, stream>>>(g, dwp, db2, out, loss);
}

// Round 8
// 528.884 us; speedup vs baseline: 7.9034x; 1.0995x over previous
//
#include <hip/hip_runtime.h>
#include <math.h>

// VQ-VAE forward. MI355X / gfx950. bf16-MFMA everywhere; conv2 now LDS-staged + XCD-swizzled.
// prep -> pack -> conv1(bf16 out) -> conv2+3(MFMA+LDS, enc out) -> vq(MFMA) -> deconv1(MFMA) -> deconv2(MFMA+LDS)
// Workspace (float slots):
//   [0)          h1b bf16 (16,777,216 slots); later g bf16 (33,554,432 slots)
//   [33554432)   enc fp32  4,194,304
//   [37748736)   qdec bf16 (2,097,152 slots)
//   [39845888)   enorm     2,048
//   [39847936)   loss      16
//   [39847952)   w2p  bf16 (262,144 slots)
//   [40110096)   dw1p bf16 (131,072 slots)
//   [40241168)   w3p  bf16 (8,192 slots)
//   [40249360)   dwp  bf16 (32,768 slots)
//   [40282128)   ebp  bf16 (65,536 slots) = bf16(-2*emb)
//   total 40,347,664 floats = 161.4 MB

typedef short s16x8 __attribute__((ext_vector_type(8)));
typedef float f32x4 __attribute__((ext_vector_type(4)));

#define LD4(p) (*(const float4*)(p))

__device__ __forceinline__ float leaky(float v) { return v >= 0.f ? v : 0.01f * v; }
__device__ __forceinline__ unsigned short f2b(float f) {
    union { float f; unsigned u; } v; v.f = f;
    unsigned r = v.u + 0x7fffu + ((v.u >> 16) & 1u);
    return (unsigned short)(r >> 16);
}
__device__ __forceinline__ s16x8 ldz(const unsigned short* p, bool ok) {
    s16x8 z = {0,0,0,0,0,0,0,0};
    return ok ? *(const s16x8*)p : z;
}

// ---------------------------------------------------------------- prep: enorm + ebp(-2e bf16) + loss init
__global__ __launch_bounds__(256) void k_prep(const float* __restrict__ emb,
                                              float* __restrict__ enorm, float* __restrict__ loss,
                                              unsigned short* __restrict__ ebp) {
    int t = blockIdx.x * 256 + threadIdx.x;
    if (t == 0) loss[0] = 0.f;
    if (t < 2048) {
        const float* e = emb + t * 64;
        float s = 0.f;
        #pragma unroll
        for (int h = 0; h < 64; ++h) {
            float ev = e[h];
            s += ev * ev;
            ebp[t * 64 + h] = f2b(-2.f * ev);
        }
        enorm[t] = s;
    }
}

// ---------------------------------------------------------------- pack bf16 MFMA fragments
__global__ __launch_bounds__(256) void k_pack(const float* __restrict__ w2, const float* __restrict__ dw1,
                                              const float* __restrict__ w3, const float* __restrict__ dw2,
                                              unsigned short* __restrict__ w2p, unsigned short* __restrict__ dw1p,
                                              unsigned short* __restrict__ w3p, unsigned short* __restrict__ dwp) {
    int t = blockIdx.x * 256 + threadIdx.x;
    if (t < 524288) {
        int j = t & 7, lane = (t >> 3) & 63, nsg = (t >> 9) & 15, cc = (t >> 13) & 3, tap = t >> 15;
        int c = cc * 32 + ((lane >> 4) << 3) + j;
        int oc = nsg * 16 + (lane & 15);
        w2p[t] = f2b(w2[(tap * 128 + c) * 256 + oc]);
    } else if (t < 786432) {
        int u = t - 524288;
        int j = u & 7, lane = (u >> 3) & 63, nsg = (u >> 9) & 15, cc = (u >> 13) & 1, tap = u >> 14;
        int c = cc * 32 + ((lane >> 4) << 3) + j;
        int oc = nsg * 16 + (lane & 15);
        dw1p[u] = f2b(dw1[(tap * 64 + c) * 256 + oc]);
    } else if (t < 802816) {
        int v = t - 786432;
        int j = v & 7, lane = (v >> 3) & 63, ks = (v >> 9) & 7, wv = v >> 12;
        int c = ks * 32 + ((lane >> 4) << 3) + j;
        int d = wv * 16 + (lane & 15);
        w3p[v] = f2b(w3[c * 64 + d]);
    } else {
        int u2 = t - 802816;  // 65536
        int j = u2 & 7, lane = (u2 >> 3) & 63, ks = (u2 >> 9) & 31, par = u2 >> 14;
        int py = par >> 1, px0 = par & 1;
        int k = ks * 32 + ((lane >> 4) << 3) + j;
        int tap = k >> 8, c = k & 255;
        int ky = py + 2 * (tap >> 1), kx = px0 + 2 * (tap & 1);
        int oc = lane & 15;
        dwp[u2] = (oc < 3) ? f2b(dw2[((ky * 4 + kx) * 256 + c) * 3 + oc]) : (unsigned short)0;
    }
}

// ---------------------------------------------------------------- conv1: x[16,256,256,3] -> h1b bf16[16,128,128,128]
__global__ __launch_bounds__(128) void k_conv1(const float* __restrict__ x, const float* __restrict__ w1,
                                               const float* __restrict__ b1, unsigned short* __restrict__ h1b) {
    __shared__ float smem[120]; // [iy 4][ix 10][c 3]
    int bx = blockIdx.x;
    int xg = bx & 31, y = (bx >> 5) & 127, b = bx >> 12;
    int x0 = xg << 2;
    int tid = threadIdx.x;
    if (tid < 120) {
        int c = tid % 3, sp = tid / 3;
        int iy = sp / 10, ix = sp - iy * 10;
        int gy = 2 * y - 1 + iy, gx = 2 * x0 - 1 + ix;
        float v = 0.f;
        if ((unsigned)gy < 256u && (unsigned)gx < 256u)
            v = x[((b * 256 + gy) * 256 + gx) * 3 + c];
        smem[tid] = v;
    }
    __syncthreads();
    int o = tid;
    float a0 = 0.f, a1 = 0.f, a2 = 0.f, a3 = 0.f;
    #pragma unroll
    for (int ky = 0; ky < 4; ++ky)
        #pragma unroll
        for (int kx = 0; kx < 4; ++kx)
            #pragma unroll
            for (int c = 0; c < 3; ++c) {
                float wv = w1[((ky * 4 + kx) * 3 + c) * 128 + o];
                a0 += smem[(ky * 10 + kx + 0) * 3 + c] * wv;
                a1 += smem[(ky * 10 + kx + 2) * 3 + c] * wv;
                a2 += smem[(ky * 10 + kx + 4) * 3 + c] * wv;
                a3 += smem[(ky * 10 + kx + 6) * 3 + c] * wv;
            }
    float bb = b1[o];
    int ob = ((b * 128 + y) * 128 + x0) * 128 + o;
    h1b[ob]       = f2b(leaky(a0 + bb));
    h1b[ob + 128] = f2b(leaky(a1 + bb));
    h1b[ob + 256] = f2b(leaky(a2 + bb));
    h1b[ob + 384] = f2b(leaky(a3 + bb));
}

// ---------------------------------------------------------------- conv2 MFMA (LDS-staged) + fused conv3
// Block (XCD-swizzled) = (b, y0): one output row (64 px) x 256 oc. 4 waves x 64 oc.
// h1 rows double-buffered in LDS: slot s = gx+1 in [0,129], swizzle cg ^= (s>>1)&15.
__global__ __launch_bounds__(256) void k_conv2(const unsigned short* __restrict__ h1b,
                                               const unsigned short* __restrict__ w2p,
                                               const float* __restrict__ b2,
                                               const unsigned short* __restrict__ w3p,
                                               const float* __restrict__ b3,
                                               float* __restrict__ enc) {
    __shared__ unsigned short stg[2][132 * 128];   // 67.6 KB; stg[0] reused as h2s (64x256) in epilogue
    int bx = blockIdx.x;
    int swz = (bx & 7) * 128 + (bx >> 3);          // XCD-chunked: contiguous (b,y0) per XCD
    int y0 = swz & 63, b = swz >> 6;
    int tid = threadIdx.x;
    int wv = tid >> 6, lane = tid & 63;
    int lr = lane & 15, lk = lane >> 4;
    f32x4 acc[4][4];
    #pragma unroll
    for (int i = 0; i < 4; ++i)
        #pragma unroll
        for (int j = 0; j < 4; ++j) acc[i][j] = (f32x4){0.f, 0.f, 0.f, 0.f};

    const unsigned short* hbase = h1b + (size_t)b * (128 * 128 * 128);

    // ---- stage row 0 into buf0
    {
        int gy = 2 * y0 - 1;
        bool ok = (unsigned)gy < 128u;
        const unsigned short* rowp = hbase + gy * (128 * 128);
        #pragma unroll
        for (int it = 0; it < 8; ++it) {
            int e = it * 256 + tid;
            int cg = e & 15, px = e >> 4;
            int s = px + 1;
            s16x8 v = ldz(rowp + px * 128 + cg * 8, ok);
            *(s16x8*)(stg[0] + s * 128 + (((cg ^ ((s >> 1) & 15))) << 3)) = v;
        }
        if (tid < 32) {
            int cg = tid & 15, s = (tid >> 4) ? 129 : 0;
            s16x8 z = {0,0,0,0,0,0,0,0};
            *(s16x8*)(stg[0] + s * 128 + (((cg ^ ((s >> 1) & 15))) << 3)) = z;
        }
    }
    __syncthreads();

    #pragma unroll
    for (int ky = 0; ky < 4; ++ky) {
        int bufi = ky & 1;
        // ---- issue next-row loads (T14 split: loads early, ds_write after compute)
        s16x8 pre[8];
        bool nok = false;
        const unsigned short* nrowp = nullptr;
        if (ky < 3) {
            int gy = 2 * y0 + ky;            // row for ky+1: 2*y0+(ky+1)-1
            nok = (unsigned)gy < 128u;
            nrowp = hbase + gy * (128 * 128);
            #pragma unroll
            for (int it = 0; it < 8; ++it) {
                int e = it * 256 + tid;
                int cg = e & 15, px = e >> 4;
                pre[it] = ldz(nrowp + px * 128 + cg * 8, nok);
            }
        }
        // ---- compute on bufi
        #pragma unroll
        for (int kx = 0; kx < 4; ++kx) {
            int tap = ky * 4 + kx;
            #pragma unroll
            for (int cc = 0; cc < 4; ++cc) {
                s16x8 aF[4];
                #pragma unroll
                for (int ms = 0; ms < 4; ++ms) {
                    int s = 2 * lr + kx + ms * 32;
                    aF[ms] = *(const s16x8*)(stg[bufi] + s * 128 + ((((cc * 4 + lk) ^ ((s >> 1) & 15))) << 3));
                }
                const unsigned short* wp = w2p + (((tap * 4 + cc) * 16 + wv * 4) * 64 + lane) * 8;
                s16x8 bF[4];
                #pragma unroll
                for (int ns = 0; ns < 4; ++ns) bF[ns] = *(const s16x8*)(wp + ns * 512);
                #pragma unroll
                for (int ms = 0; ms < 4; ++ms)
                    #pragma unroll
                    for (int ns = 0; ns < 4; ++ns)
                        acc[ms][ns] = __builtin_amdgcn_mfma_f32_16x16x32_bf16(aF[ms], bF[ns], acc[ms][ns], 0, 0, 0);
            }
        }
        // ---- write staged regs to other buffer, sync
        if (ky < 3) {
            #pragma unroll
            for (int it = 0; it < 8; ++it) {
                int e = it * 256 + tid;
                int cg = e & 15, px = e >> 4;
                int s = px + 1;
                *(s16x8*)(stg[bufi ^ 1] + s * 128 + (((cg ^ ((s >> 1) & 15))) << 3)) = pre[it];
            }
            if (tid < 32) {
                int cg = tid & 15, s = (tid >> 4) ? 129 : 0;
                s16x8 z = {0,0,0,0,0,0,0,0};
                *(s16x8*)(stg[bufi ^ 1] + s * 128 + (((cg ^ ((s >> 1) & 15))) << 3)) = z;
            }
            __syncthreads();
        }
    }

    // epilogue 1: bias + leaky -> bf16 LDS tile (h2s aliases stg[0]; last compute read stg[1])
    unsigned short* h2s = stg[0];
    int ocb = wv * 64;
    #pragma unroll
    for (int ns = 0; ns < 4; ++ns) {
        int c = ocb + ns * 16 + lr;
        float bb = b2[c];
        int cg = c >> 3, cj = c & 7;
        #pragma unroll
        for (int ms = 0; ms < 4; ++ms)
            #pragma unroll
            for (int r = 0; r < 4; ++r) {
                int px = ms * 16 + lk * 4 + r;
                h2s[px * 256 + ((cg ^ (px & 31)) << 3) + cj] = f2b(leaky(acc[ms][ns][r] + bb));
            }
    }
    __syncthreads();
    // conv3: 64px x 64d, K=256. Wave wv covers d = wv*16 + (0..15).
    f32x4 a3[4];
    #pragma unroll
    for (int i = 0; i < 4; ++i) a3[i] = (f32x4){0.f, 0.f, 0.f, 0.f};
    #pragma unroll
    for (int ks = 0; ks < 8; ++ks) {
        s16x8 bF = *(const s16x8*)(w3p + ((wv * 8 + ks) * 64 + lane) * 8);
        int cg = ks * 4 + lk;
        #pragma unroll
        for (int ms = 0; ms < 4; ++ms) {
            int px = lr + ms * 16;
            s16x8 aF = *(const s16x8*)(h2s + px * 256 + ((cg ^ (px & 31)) << 3));
            a3[ms] = __builtin_amdgcn_mfma_f32_16x16x32_bf16(aF, bF, a3[ms], 0, 0, 0);
        }
    }
    float bb3 = b3[wv * 16 + lr];
    float* outp = enc + ((size_t)(b * 64 + y0)) * 64 * 64;
    #pragma unroll
    for (int ms = 0; ms < 4; ++ms)
        #pragma unroll
        for (int r = 0; r < 4; ++r) {
            int px = ms * 16 + lk * 4 + r;
            outp[px * 64 + wv * 16 + lr] = a3[ms][r] + bb3;
        }
}

// ---------------------------------------------------------------- fused VQ via MFMA: dist+argmin+scatter+loss
__global__ __launch_bounds__(256) void k_vq(const float* __restrict__ enc, const unsigned short* __restrict__ ebp,
                                            const float* __restrict__ emb, const float* __restrict__ enorm,
                                            unsigned short* __restrict__ qdec, float* __restrict__ loss) {
    __shared__ unsigned short f_sw[64 * 64];  // [row c][h], XOR-swizzled 8-elem groups (8 KB)
    __shared__ float en_sh[2048];             // 8 KB
    __shared__ float red_s[4 * 64];
    __shared__ int   red_k[4 * 64];
    __shared__ int   bk_sh[64];

    int rb = blockIdx.x;
    int b = rb >> 6, w = rb & 63;
    int tid = threadIdx.x;
    int cl = tid & 63, hg = tid >> 6;

    const float* encb = enc + b * 262144 + w * 64;
    #pragma unroll
    for (int hp = 0; hp < 16; ++hp) {
        int h = hp * 4 + hg;
        f_sw[cl * 64 + ((((h >> 3) ^ (cl & 7)) << 3) | (h & 7))] = f2b(encb[h * 4096 + cl]);
    }
    #pragma unroll
    for (int j = 0; j < 8; ++j) {
        int e = j * 256 + tid;
        en_sh[e] = enorm[e];
    }
    __syncthreads();

    int wv = tid >> 6, lane = tid & 63, lr = lane & 15, lk = lane >> 4;
    s16x8 aF[4][2];
    #pragma unroll
    for (int ms = 0; ms < 4; ++ms)
        #pragma unroll
        for (int ks = 0; ks < 2; ++ks) {
            int row = ms * 16 + lr;
            int grp = ((ks << 2) | lk) ^ (row & 7);
            aF[ms][ks] = *(const s16x8*)(f_sw + row * 64 + (grp << 3));
        }

    float bs[4][4]; int bkr[4][4];
    #pragma unroll
    for (int ms = 0; ms < 4; ++ms)
        #pragma unroll
        for (int r = 0; r < 4; ++r) { bs[ms][r] = 3.4e38f; bkr[ms][r] = 0; }

    const unsigned short* ebw = ebp + (size_t)(wv * 512) * 64;
    #pragma unroll 1
    for (int j = 0; j < 32; ++j) {
        const unsigned short* ep = ebw + (j * 16 + lr) * 64 + lk * 8;
        s16x8 bF0 = *(const s16x8*)(ep);
        s16x8 bF1 = *(const s16x8*)(ep + 32);
        int kg = wv * 512 + j * 16 + lr;
        float en = en_sh[kg];
        #pragma unroll
        for (int ms = 0; ms < 4; ++ms) {
            f32x4 d = {en, en, en, en};
            d = __builtin_amdgcn_mfma_f32_16x16x32_bf16(aF[ms][0], bF0, d, 0, 0, 0);
            d = __builtin_amdgcn_mfma_f32_16x16x32_bf16(aF[ms][1], bF1, d, 0, 0, 0);
            #pragma unroll
            for (int r = 0; r < 4; ++r) {
                if (d[r] < bs[ms][r]) { bs[ms][r] = d[r]; bkr[ms][r] = kg; }
            }
        }
    }

    #pragma unroll
    for (int off = 1; off <= 8; off <<= 1) {
        #pragma unroll
        for (int ms = 0; ms < 4; ++ms)
            #pragma unroll
            for (int r = 0; r < 4; ++r) {
                float os = __shfl_xor(bs[ms][r], off, 64);
                int ok = __shfl_xor(bkr[ms][r], off, 64);
                if (os < bs[ms][r] || (os == bs[ms][r] && ok < bkr[ms][r])) {
                    bs[ms][r] = os; bkr[ms][r] = ok;
                }
            }
    }
    if (lr == 0) {
        #pragma unroll
        for (int ms = 0; ms < 4; ++ms)
            #pragma unroll
            for (int r = 0; r < 4; ++r) {
                int row = ms * 16 + lk * 4 + r;
                red_s[wv * 64 + row] = bs[ms][r];
                red_k[wv * 64 + row] = bkr[ms][r];
            }
    }
    __syncthreads();
    if (tid < 64) {
        float s0 = red_s[tid]; int k0 = red_k[tid];
        #pragma unroll
        for (int v = 1; v < 4; ++v) {
            float s = red_s[v * 64 + tid]; int k = red_k[v * 64 + tid];
            if (s < s0 || (s == s0 && k < k0)) { s0 = s; k0 = k; }
        }
        bk_sh[tid] = k0;
    }
    __syncthreads();

    int bcode = bk_sh[cl];
    const float* ev = emb + bcode * 64;
    unsigned short* qd = qdec + b * 262144 + w * 64 + cl;
    float ls = 0.f;
    #pragma unroll
    for (int hp = 0; hp < 16; ++hp) {
        int h = hp * 4 + hg;
        float e = ev[h];
        float f = encb[h * 4096 + cl];
        float d = e - f;
        ls += d * d;
        qd[h * 4096] = f2b(e);
    }
    #pragma unroll
    for (int off = 32; off; off >>= 1) ls += __shfl_xor(ls, off, 64);
    if ((tid & 63) == 0) atomicAdd(loss, ls);
}

// ---------------------------------------------------------------- deconv1 MFMA: qdec bf16 -> g bf16[16,128,128,256]
__global__ __launch_bounds__(256) void k_deconv1(const unsigned short* __restrict__ qdec,
                                                 const unsigned short* __restrict__ dw1p,
                                                 const float* __restrict__ db1, unsigned short* __restrict__ g) {
    int bx = blockIdx.x;
    int parx = bx & 1, y = (bx >> 1) & 127, b = bx >> 8;
    int pary = y & 1;
    int h0 = (y - 2 + pary) >> 1;
    int tid = threadIdx.x;
    int wv = tid >> 6, lane = tid & 63;
    int lr = lane & 15, lk = lane >> 4;
    f32x4 acc[4][4];
    #pragma unroll
    for (int i = 0; i < 4; ++i)
        #pragma unroll
        for (int j = 0; j < 4; ++j) acc[i][j] = (f32x4){0.f, 0.f, 0.f, 0.f};

    const unsigned short* qb = qdec + (size_t)b * (64 * 64 * 64);
    #pragma unroll
    for (int tky = 0; tky < 2; ++tky) {
        int h = h0 + tky;
        bool hok = (unsigned)h < 64u;
        const unsigned short* rowp = qb + h * (64 * 64);
        #pragma unroll
        for (int tkx = 0; tkx < 2; ++tkx) {
            int tap = (pary + 2 * tky) * 4 + parx + 2 * tkx;
            int wbase = lr + parx + tkx - 1;
            #pragma unroll
            for (int cc = 0; cc < 2; ++cc) {
                int c0 = cc * 32 + lk * 8;
                s16x8 aF[4];
                #pragma unroll
                for (int ms = 0; ms < 4; ++ms) {
                    int w = wbase + ms * 16;
                    aF[ms] = ldz(rowp + w * 64 + c0, hok && (unsigned)w < 64u);
                }
                const unsigned short* wp = dw1p + (((tap * 2 + cc) * 16 + wv * 4) * 64 + lane) * 8;
                s16x8 bF[4];
                #pragma unroll
                for (int ns = 0; ns < 4; ++ns) bF[ns] = *(const s16x8*)(wp + ns * 512);
                #pragma unroll
                for (int ms = 0; ms < 4; ++ms)
                    #pragma unroll
                    for (int ns = 0; ns < 4; ++ns)
                        acc[ms][ns] = __builtin_amdgcn_mfma_f32_16x16x32_bf16(aF[ms], bF[ns], acc[ms][ns], 0, 0, 0);
            }
        }
    }
    int ocb = wv * 64;
    unsigned short* gp = g + ((size_t)(b * 128 + y)) * 128 * 256;
    #pragma unroll
    for (int ns = 0; ns < 4; ++ns) {
        float bb = db1[ocb + ns * 16 + lr];
        #pragma unroll
        for (int ms = 0; ms < 4; ++ms)
            #pragma unroll
            for (int r = 0; r < 4; ++r) {
                int u = ms * 16 + lk * 4 + r;
                int xo = 2 * u + parx;
                gp[xo * 256 + ocb + ns * 16 + lr] = f2b(leaky(acc[ms][ns][r] + bb));
            }
    }
}

// ---------------------------------------------------------------- deconv2 MFMA, LDS-staged: g bf16 -> recon fp32, tanh
__global__ __launch_bounds__(256) void k_deconv2(const unsigned short* __restrict__ g,
                                                 const unsigned short* __restrict__ dwp,
                                                 const float* __restrict__ db2, float* __restrict__ out,
                                                 const float* __restrict__ loss) {
    __shared__ unsigned short gs[2][128][128];
    int bx = blockIdx.x;
    int swz = (bx % 8) * 258 + bx / 8;        // 2064 blocks; XCD-chunked
    int b = swz / 129, m = swz % 129;
    int tid = threadIdx.x;
    int wv = tid >> 6, lane = tid & 63;
    int lr = lane & 15, lk = lane >> 4;
    int yi = wv >> 1, px0 = wv & 1;
    int y = 2 * m - 1 + yi;
    int py = yi ^ 1;

    f32x4 acc[8];
    #pragma unroll
    for (int i = 0; i < 8; ++i) acc[i] = (f32x4){0.f, 0.f, 0.f, 0.f};

    const unsigned short* gb = g + (size_t)b * (128 * 128 * 256);
    const unsigned short* dwb = dwp + (size_t)(py * 2 + px0) * 32 * 512;

    #pragma unroll 1
    for (int cc = 0; cc < 2; ++cc) {
        __syncthreads();
        #pragma unroll
        for (int i = 0; i < 16; ++i) {
            int ch = i * 256 + tid;             // 0..4095
            int cg = ch & 15;
            int w  = (ch >> 4) & 127;
            int tky = ch >> 11;
            int h = m - 1 + tky;
            s16x8 v = {0,0,0,0,0,0,0,0};
            if ((unsigned)h < 128u)
                v = *(const s16x8*)(gb + h * (128 * 256) + w * 256 + cc * 128 + cg * 8);
            *(s16x8*)(&gs[tky][w][(cg ^ (w & 15)) << 3]) = v;
        }
        __syncthreads();
        #pragma unroll
        for (int tky = 0; tky < 2; ++tky) {
            #pragma unroll
            for (int tkx = 0; tkx < 2; ++tkx) {
                int tap = tky * 2 + tkx;
                int wofs = px0 - 1 + tkx;
                #pragma unroll
                for (int k8 = 0; k8 < 4; ++k8) {
                    int ks = tap * 8 + cc * 4 + k8;
                    s16x8 bF = *(const s16x8*)(dwb + (ks * 64 + lane) * 8);
                    int cg = k8 * 4 + lk;
                    #pragma unroll
                    for (int ms = 0; ms < 8; ++ms) {
                        int w = ms * 16 + lr + wofs;
                        s16x8 aF = {0,0,0,0,0,0,0,0};
                        if ((unsigned)w < 128u)
                            aF = *(const s16x8*)(&gs[tky][w][(cg ^ (w & 15)) << 3]);
                        acc[ms] = __builtin_amdgcn_mfma_f32_16x16x32_bf16(aF, bF, acc[ms], 0, 0, 0);
                    }
                }
            }
        }
    }
    if ((unsigned)y < 256u && lr < 3) {
        float bb = db2[lr];
        #pragma unroll
        for (int ms = 0; ms < 8; ++ms)
            #pragma unroll
            for (int r = 0; r < 4; ++r) {
                int n = ms * 16 + lk * 4 + r;
                int x = 2 * n + px0;
                out[((size_t)b * 65536 + y * 256 + x) * 3 + lr] = tanhf(acc[ms][r] + bb);
            }
    }
    if (bx == 0 && tid == 0)
        out[3145728] = loss[0] * (1.25f / 4194304.f);
}

// ---------------------------------------------------------------- launch
extern "C" void kernel_launch(void* const* d_in, const int* in_sizes, int n_in,
                              void* d_out, int out_size, void* d_ws, size_t ws_size,
                              hipStream_t stream) {
    const float* x   = (const float*)d_in[0];
    const float* emb = (const float*)d_in[1];
    const float* w1  = (const float*)d_in[2];
    const float* b1  = (const float*)d_in[3];
    const float* w2  = (const float*)d_in[4];
    const float* b2  = (const float*)d_in[5];
    const float* w3  = (const float*)d_in[6];
    const float* b3  = (const float*)d_in[7];
    const float* dw1 = (const float*)d_in[8];
    const float* db1 = (const float*)d_in[9];
    const float* dw2 = (const float*)d_in[10];
    const float* db2 = (const float*)d_in[11];
    float* out = (float*)d_out;
    float* ws  = (float*)d_ws;

    if (ws_size < (size_t)40347664 * 4) return;

    unsigned short* h1b  = (unsigned short*)ws;            // bf16, later overlapped by g
    unsigned short* g    = (unsigned short*)ws;            // bf16 [16,128,128,256]
    float* enc   = ws + 33554432;
    unsigned short* qdec = (unsigned short*)(ws + 37748736);
    float* enorm = ws + 39845888;
    float* loss  = ws + 39847936;
    unsigned short* w2p  = (unsigned short*)(ws + 39847952);
    unsigned short* dw1p = (unsigned short*)(ws + 40110096);
    unsigned short* w3p  = (unsigned short*)(ws + 40241168);
    unsigned short* dwp  = (unsigned short*)(ws + 40249360);
    unsigned short* ebp  = (unsigned short*)(ws + 40282128);

    k_prep   <<<8,     256, 0, stream>>>(emb, enorm, loss, ebp);
    k_pack   <<<3392,  256, 0, stream>>>(w2, dw1, w3, dw2, w2p, dw1p, w3p, dwp);
    k_conv1  <<<65536, 128, 0, stream>>>(x, w1, b1, h1b);
    k_conv2  <<<1024,  256, 0, stream>>>(h1b, w2p, b2, w3p, b3, enc);
    k_vq     <<<1024,  256, 0, stream>>>(enc, ebp, emb, enorm, qdec, loss);
    k_deconv1<<<4096,  256, 0, stream>>>(qdec, dw1p, db1, g);
    k_deconv2<<<2064,  256, 0, stream>>>(g, dwp, db2, out, loss);
}